// Round 10
// baseline (596.350 us; speedup 1.0000x reference)
//
#include <hip/hip_runtime.h>
#include <hip/hip_bf16.h>

#define N_NODES 50000
#define N_EDGESX 1600000
#define E_TOT   (N_EDGESX + N_NODES)
#define IN_DIM 128
#define HID 64
#define HEADS 4
#define HC 256
#define N_GRAPHS 64
#define OUT_DIM 10
#define NEG_SLOPE 0.2f

#define NBUK 196
#define CAP 12288
#define BT 4096

typedef __attribute__((ext_vector_type(8))) short bf16x8;
typedef __attribute__((ext_vector_type(4))) float f32x4;

__device__ __forceinline__ float lrelu(float x){ return fmaxf(x, NEG_SLOPE*x); }
__device__ __forceinline__ float sel4(float4 v, int i){
  float r = v.x;
  r = (i==1) ? v.y : r;
  r = (i==2) ? v.z : r;
  r = (i==3) ? v.w : r;
  return r;
}
__device__ __forceinline__ unsigned short f2bf(float f){
  union { __hip_bfloat16 b; unsigned short u; } cv;
  cv.b = __float2bfloat16(f);
  return cv.u;
}
__device__ __forceinline__ float bf2f(unsigned short u){ return __uint_as_float(((unsigned)u) << 16); }
__device__ __forceinline__ float bflo(unsigned int u){ return __uint_as_float(u << 16); }
__device__ __forceinline__ float bfhi(unsigned int u){ return __uint_as_float(u & 0xffff0000u); }

// ---------------- CSR build: LDS-binned counting sort ----------------
__global__ __launch_bounds__(256) void bin_k(const int* __restrict__ ei,
                                             int* __restrict__ bucket_cursor,
                                             unsigned int* __restrict__ bucket_buf){
  __shared__ unsigned int pk[BT];
  __shared__ unsigned int binned[BT];
  __shared__ int hist[256], excl[256], gbase[256], lcur[256], tmp[256];
  const int tid = threadIdx.x;
  const int e0 = blockIdx.x * BT;
  const int nv = min(BT, E_TOT - e0);
  hist[tid] = 0;
  __syncthreads();
  for (int i = tid; i < nv; i += 256){
    int e = e0 + i;
    int src, dst;
    if (e < N_EDGESX){ src = ei[e]; dst = ei[N_EDGESX + e]; }
    else { src = e - N_EDGESX; dst = src; }
    pk[i] = ((unsigned)src << 16) | (unsigned)dst;
    atomicAdd(&hist[dst >> 8], 1);
  }
  __syncthreads();
  int v = hist[tid];
  tmp[tid] = v;
  __syncthreads();
  for (int off = 1; off < 256; off <<= 1){
    int t = (tid >= off) ? tmp[tid-off] : 0;
    __syncthreads();
    tmp[tid] += t;
    __syncthreads();
  }
  excl[tid] = tmp[tid] - v;
  lcur[tid] = tmp[tid] - v;
  if (tid < NBUK && v > 0) gbase[tid] = atomicAdd(&bucket_cursor[tid], v);
  __syncthreads();
  for (int i = tid; i < nv; i += 256){
    unsigned u = pk[i];
    int b = (int)((u & 0xFFFFu) >> 8);
    int p = atomicAdd(&lcur[b], 1);
    binned[p] = u;
  }
  __syncthreads();
  for (int j = tid; j < nv; j += 256){
    unsigned u = binned[j];
    int b = (int)((u & 0xFFFFu) >> 8);
    bucket_buf[(size_t)b*CAP + gbase[b] + (j - excl[b])] = u;
  }
}

__global__ __launch_bounds__(256) void bucket_scan_k(const int* __restrict__ bucket_cursor,
                                                     int* __restrict__ bucket_base,
                                                     int* __restrict__ row_start){
  __shared__ int tmp[256];
  int t = threadIdx.x;
  int v = (t < NBUK) ? bucket_cursor[t] : 0;
  tmp[t] = v;
  __syncthreads();
  for (int off = 1; off < 256; off <<= 1){
    int x = (t >= off) ? tmp[t-off] : 0;
    __syncthreads();
    tmp[t] += x;
    __syncthreads();
  }
  if (t < NBUK) bucket_base[t] = tmp[t] - v;
  if (t == 0) row_start[N_NODES] = E_TOT;
}

__global__ __launch_bounds__(256) void build_k(const unsigned int* __restrict__ bucket_buf,
                                               const int* __restrict__ bucket_cursor,
                                               const int* __restrict__ bucket_base,
                                               int* __restrict__ row_start,
                                               int* __restrict__ csr_src){
  __shared__ int hist[256], excl[256], lcur[256], tmp[256];
  const int b = blockIdx.x;
  const int t = threadIdx.x;
  const int cntb = bucket_cursor[b];
  const int base = bucket_base[b];
  const unsigned int* buf = bucket_buf + (size_t)b*CAP;
  hist[t] = 0;
  __syncthreads();
  for (int i = t; i < cntb; i += 256) atomicAdd(&hist[buf[i] & 255], 1);
  __syncthreads();
  int v = hist[t];
  tmp[t] = v;
  __syncthreads();
  for (int off = 1; off < 256; off <<= 1){
    int x = (t >= off) ? tmp[t-off] : 0;
    __syncthreads();
    tmp[t] += x;
    __syncthreads();
  }
  excl[t] = tmp[t] - v;
  lcur[t] = tmp[t] - v;
  int g = b*256 + t;
  if (g < N_NODES) row_start[g] = base + excl[t];
  __syncthreads();
  for (int i = t; i < cntb; i += 256){
    unsigned u = buf[i];
    int p = atomicAdd(&lcur[u & 255], 1);
    csr_src[base + p] = (int)(u >> 16);
  }
}

// ---------------- fused weight prep: WT0/WT1/WT2 transpose->bf16 + layer-0 score projection ----------------
__global__ __launch_bounds__(256) void prep_k(const float* __restrict__ W0, const float* __restrict__ W1,
                                              const float* __restrict__ W2,
                                              const float* __restrict__ as0, const float* __restrict__ ad0,
                                              unsigned short* __restrict__ WT0, unsigned short* __restrict__ WT1,
                                              unsigned short* __restrict__ WT2,
                                              float* __restrict__ ws0, float* __restrict__ wd0){
  const int b = blockIdx.x, t = threadIdx.x;
  if (b < 64){
    int idx = b*256 + t;
    int k = idx >> 8, c = idx & 255;
    WT0[c*64 + k] = f2bf(W0[k*256 + c]);
  } else if (b < 320){
    int idx = (b-64)*256 + t;
    int k = idx >> 8, c = idx & 255;
    WT1[c*256 + k] = f2bf(W1[k*256 + c]);
  } else if (b < 576){
    int idx = (b-320)*256 + t;
    int k = idx >> 8, c = idx & 255;
    WT2[c*256 + k] = f2bf(W2[k*256 + c]);
  } else {
    int h = t >> 6, k = t & 63;
    float s = 0.f, d = 0.f;
    for (int c = 0; c < 64; c++){
      float wv = W0[k*256 + h*64 + c];
      s = fmaf(wv, as0[h*64 + c], s);
      d = fmaf(wv, ad0[h*64 + c], d);
    }
    ws0[t] = s; wd0[t] = d;
  }
}

// ---------------- aggregator linear + fused layer-0 scores ----------------
__global__ __launch_bounds__(256) void agg_lin(const float* __restrict__ imgs, const float* __restrict__ W,
                                               const float* __restrict__ b,
                                               const float* __restrict__ ws0, const float* __restrict__ wd0,
                                               unsigned short* __restrict__ x0,
                                               float* __restrict__ es, float* __restrict__ ed){
  __shared__ __align__(16) float xr[4][IN_DIM];
  int w = threadIdx.x >> 6, lane = threadIdx.x & 63;
  int n = blockIdx.x*4 + w;
  if (n >= N_NODES) return;
  ((float2*)xr[w])[lane] = ((const float2*)(imgs + (size_t)n*IN_DIM))[lane];
  float acc = b[lane];
  #pragma unroll 8
  for (int k = 0; k < IN_DIM; k++)
    acc = fmaf(xr[w][k], W[k*HID + lane], acc);
  x0[(size_t)n*HID + lane] = f2bf(acc);
  float p[4], q[4];
  #pragma unroll
  for (int h = 0; h < 4; h++){
    p[h] = acc * ws0[h*64 + lane];
    q[h] = acc * wd0[h*64 + lane];
  }
  #pragma unroll
  for (int off = 32; off >= 1; off >>= 1){
    #pragma unroll
    for (int h = 0; h < 4; h++){
      p[h] += __shfl_xor(p[h], off);
      q[h] += __shfl_xor(q[h], off);
    }
  }
  if (lane == 0){
    float4 pv; pv.x=p[0]; pv.y=p[1]; pv.z=p[2]; pv.w=p[3];
    float4 qv; qv.x=q[0]; qv.y=q[1]; qv.z=q[2]; qv.w=q[3];
    *(float4*)(es + n*4) = pv;
    *(float4*)(ed + n*4) = qv;
  }
}

// ---------------- layer-0 aggregation: gather x0 (128B rows), 4-head weighted sums ----------------
__global__ __launch_bounds__(256) void gat_agg0(const unsigned short* __restrict__ x0,
    const float* __restrict__ es, const float* __restrict__ ed,
    const int* __restrict__ row_start, const int* __restrict__ csr_src,
    unsigned short* __restrict__ y4){
  __shared__ int   sbuf[4][64];
  __shared__ float wbuf[4][64][4];
  const int lane = threadIdx.x & 63;
  const int wid  = threadIdx.x >> 6;
  const int n = blockIdx.x*4 + wid;
  if (n >= N_NODES) return;
  const int rs = row_start[n], re = row_start[n+1];
  const float4 edn = *(const float4*)(ed + n*4);
  const int slot = lane >> 3;
  const int f8   = lane & 7;
  float4 sumw = make_float4(0.f,0.f,0.f,0.f);
  float acc[4][8];
  #pragma unroll
  for (int h=0;h<4;h++)
    #pragma unroll
    for (int q2=0;q2<8;q2++) acc[h][q2]=0.f;

  for (int base = rs; base < re; base += 64){
    const int cl = min(64, re - base);
    int e = base + lane;
    int s = (e < re) ? csr_src[e] : 0;
    float4 e4 = *(const float4*)(es + (s<<2));
    float w0 = __expf(lrelu(e4.x + edn.x));
    float w1 = __expf(lrelu(e4.y + edn.y));
    float w2 = __expf(lrelu(e4.z + edn.z));
    float w3 = __expf(lrelu(e4.w + edn.w));
    if (e >= re){ w0=0.f; w1=0.f; w2=0.f; w3=0.f; }
    sumw.x += w0; sumw.y += w1; sumw.z += w2; sumw.w += w3;
    sbuf[wid][lane] = s;
    float4 wv; wv.x=w0; wv.y=w1; wv.z=w2; wv.w=w3;
    *(float4*)wbuf[wid][lane] = wv;
    int j = 0;
    for (; j + 16 <= cl; j += 16){
      int j0 = j + slot, j1 = j + 8 + slot;
      float4 awA = *(const float4*)wbuf[wid][j0]; int sA = sbuf[wid][j0];
      float4 awB = *(const float4*)wbuf[wid][j1]; int sB = sbuf[wid][j1];
      uint4 hvA = *(const uint4*)(x0 + ((unsigned)(sA<<6) + (unsigned)(f8<<3)));
      uint4 hvB = *(const uint4*)(x0 + ((unsigned)(sB<<6) + (unsigned)(f8<<3)));
      float fA[8] = {bflo(hvA.x),bfhi(hvA.x),bflo(hvA.y),bfhi(hvA.y),
                     bflo(hvA.z),bfhi(hvA.z),bflo(hvA.w),bfhi(hvA.w)};
      float fB[8] = {bflo(hvB.x),bfhi(hvB.x),bflo(hvB.y),bfhi(hvB.y),
                     bflo(hvB.z),bfhi(hvB.z),bflo(hvB.w),bfhi(hvB.w)};
      #pragma unroll
      for (int q2=0;q2<8;q2++){
        acc[0][q2] = fmaf(awA.x, fA[q2], acc[0][q2]);
        acc[1][q2] = fmaf(awA.y, fA[q2], acc[1][q2]);
        acc[2][q2] = fmaf(awA.z, fA[q2], acc[2][q2]);
        acc[3][q2] = fmaf(awA.w, fA[q2], acc[3][q2]);
      }
      #pragma unroll
      for (int q2=0;q2<8;q2++){
        acc[0][q2] = fmaf(awB.x, fB[q2], acc[0][q2]);
        acc[1][q2] = fmaf(awB.y, fB[q2], acc[1][q2]);
        acc[2][q2] = fmaf(awB.z, fB[q2], acc[2][q2]);
        acc[3][q2] = fmaf(awB.w, fB[q2], acc[3][q2]);
      }
    }
    for (; j < cl; j += 8){
      int jj = j + slot;
      if (jj < cl){
        float4 aw = *(const float4*)wbuf[wid][jj];
        int s2 = sbuf[wid][jj];
        uint4 hv = *(const uint4*)(x0 + ((unsigned)(s2<<6) + (unsigned)(f8<<3)));
        float f[8] = {bflo(hv.x),bfhi(hv.x),bflo(hv.y),bfhi(hv.y),
                      bflo(hv.z),bfhi(hv.z),bflo(hv.w),bfhi(hv.w)};
        #pragma unroll
        for (int q2=0;q2<8;q2++){
          acc[0][q2] = fmaf(aw.x, f[q2], acc[0][q2]);
          acc[1][q2] = fmaf(aw.y, f[q2], acc[1][q2]);
          acc[2][q2] = fmaf(aw.z, f[q2], acc[2][q2]);
          acc[3][q2] = fmaf(aw.w, f[q2], acc[3][q2]);
        }
      }
    }
  }
  #pragma unroll
  for (int off = 8; off <= 32; off <<= 1){
    #pragma unroll
    for (int h=0;h<4;h++)
      #pragma unroll
      for (int q2=0;q2<8;q2++) acc[h][q2] += __shfl_xor(acc[h][q2], off);
  }
  #pragma unroll
  for (int off = 32; off >= 1; off >>= 1){
    sumw.x += __shfl_xor(sumw.x, off);
    sumw.y += __shfl_xor(sumw.y, off);
    sumw.z += __shfl_xor(sumw.z, off);
    sumw.w += __shfl_xor(sumw.w, off);
  }
  if (lane < 32){
    int h = lane >> 3;
    float inv = 1.f / (sel4(sumw, h) + 1e-16f);
    union { unsigned short u[8]; uint4 v; } ob;
    #pragma unroll
    for (int q2=0;q2<8;q2++) ob.u[q2] = f2bf(acc[h][q2] * inv);
    *(uint4*)(y4 + (size_t)n*HC + lane*8) = ob.v;
  }
}

// ---------------- fused: x1 = ELU(y4@W0_bd + b0) in LDS, then h1 = x1@W1 + scores ----------------
__global__ __launch_bounds__(256) void hfuse_k(const unsigned short* __restrict__ y4,
                                               const unsigned short* __restrict__ WT0,
                                               const float* __restrict__ b0,
                                               const unsigned short* __restrict__ WT1,
                                               const float* __restrict__ as_, const float* __restrict__ ad_,
                                               unsigned short* __restrict__ h,
                                               float* __restrict__ es, float* __restrict__ ed){
  __shared__ __align__(16) unsigned short xs[16][264];
  __shared__ __align__(16) unsigned short x1s[16][264];
  const int tid = threadIdx.x;
  const int lane = tid & 63;
  const int w = tid >> 6;
  const int n0 = blockIdx.x * 16;
  for (int i = tid; i < 16*32; i += 256){
    int r = i >> 5, cc = (i & 31) * 8;
    *(uint4*)(&xs[r][cc]) = *(const uint4*)(y4 + (size_t)(n0+r)*HC + cc);
  }
  __syncthreads();
  const int g = lane >> 4, cl = lane & 15;
  {
    f32x4 acc[4];
    #pragma unroll
    for (int c = 0; c < 4; c++) acc[c] = (f32x4){0.f,0.f,0.f,0.f};
    #pragma unroll
    for (int t = 0; t < 2; t++){
      bf16x8 a = *(const bf16x8*)(&xs[cl][w*64 + t*32 + g*8]);
      #pragma unroll
      for (int c = 0; c < 4; c++){
        bf16x8 bv = *(const bf16x8*)(WT0 + (size_t)(w*64 + c*16 + cl)*64 + t*32 + g*8);
        acc[c] = __builtin_amdgcn_mfma_f32_16x16x32_bf16(a, bv, acc[c], 0, 0, 0);
      }
    }
    #pragma unroll
    for (int c = 0; c < 4; c++){
      int col = w*64 + c*16 + cl;
      float bb = b0[col];
      #pragma unroll
      for (int j = 0; j < 4; j++){
        float v = acc[c][j] + bb;
        v = v > 0.f ? v : expm1f(v);
        x1s[g*4 + j][col] = f2bf(v);
      }
    }
  }
  __syncthreads();
  f32x4 acc[4];
  #pragma unroll
  for (int c = 0; c < 4; c++) acc[c] = (f32x4){0.f,0.f,0.f,0.f};
  #pragma unroll
  for (int t = 0; t < 8; t++){
    bf16x8 a = *(const bf16x8*)(&x1s[cl][t*32 + g*8]);
    #pragma unroll
    for (int c = 0; c < 4; c++){
      bf16x8 bv = *(const bf16x8*)(WT1 + (size_t)(w*64 + c*16 + cl)*HC + t*32 + g*8);
      acc[c] = __builtin_amdgcn_mfma_f32_16x16x32_bf16(a, bv, acc[c], 0, 0, 0);
    }
  }
  float pes[4] = {0.f,0.f,0.f,0.f}, ped[4] = {0.f,0.f,0.f,0.f};
  #pragma unroll
  for (int c = 0; c < 4; c++){
    float av = as_[w*64 + c*16 + cl];
    float dv = ad_[w*64 + c*16 + cl];
    #pragma unroll
    for (int j = 0; j < 4; j++){
      pes[j] = fmaf(acc[c][j], av, pes[j]);
      ped[j] = fmaf(acc[c][j], dv, ped[j]);
    }
  }
  #pragma unroll
  for (int off = 8; off >= 1; off >>= 1){
    #pragma unroll
    for (int j = 0; j < 4; j++){
      pes[j] += __shfl_xor(pes[j], off);
      ped[j] += __shfl_xor(ped[j], off);
    }
  }
  if (cl == 0){
    #pragma unroll
    for (int j = 0; j < 4; j++){
      int n = n0 + g*4 + j;
      es[n*4 + w] = pes[j];
      ed[n*4 + w] = ped[j];
    }
  }
  #pragma unroll
  for (int c = 0; c < 4; c++){
    #pragma unroll
    for (int j = 0; j < 4; j++){
      h[(size_t)(n0 + g*4 + j)*HC + w*64 + c*16 + cl] = f2bf(acc[c][j]);
    }
  }
}

// ---------------- MFMA GAT linear + fused scores; h NODE-major [N,256] ----------------
template<int K>
__global__ __launch_bounds__(256) void lin_mfma(const unsigned short* __restrict__ x,
                                                const unsigned short* __restrict__ WT,
                                                const float* __restrict__ as_, const float* __restrict__ ad_,
                                                unsigned short* __restrict__ h,
                                                float* __restrict__ es, float* __restrict__ ed){
  constexpr int KP = K + 8;
  __shared__ __align__(16) unsigned short xs[16][KP];
  const int tid = threadIdx.x;
  const int lane = tid & 63;
  const int w = tid >> 6;
  const int n0 = blockIdx.x * 16;
  constexpr int CH = K/8;
  for (int i = tid; i < 16*CH; i += 256){
    int r = i / CH, cc = (i % CH)*8;
    *(uint4*)(&xs[r][cc]) = *(const uint4*)(x + (size_t)(n0+r)*K + cc);
  }
  __syncthreads();
  const int g  = lane >> 4;
  const int cl = lane & 15;
  f32x4 acc[4];
  #pragma unroll
  for (int c = 0; c < 4; c++) acc[c] = (f32x4){0.f,0.f,0.f,0.f};
  #pragma unroll
  for (int t = 0; t < K/32; t++){
    bf16x8 a = *(const bf16x8*)(&xs[cl][t*32 + g*8]);
    #pragma unroll
    for (int c = 0; c < 4; c++){
      bf16x8 bv = *(const bf16x8*)(WT + (size_t)(w*64 + c*16 + cl)*K + t*32 + g*8);
      acc[c] = __builtin_amdgcn_mfma_f32_16x16x32_bf16(a, bv, acc[c], 0, 0, 0);
    }
  }
  float pes[4] = {0.f,0.f,0.f,0.f}, ped[4] = {0.f,0.f,0.f,0.f};
  #pragma unroll
  for (int c = 0; c < 4; c++){
    float av = as_[w*64 + c*16 + cl];
    float dv = ad_[w*64 + c*16 + cl];
    #pragma unroll
    for (int j = 0; j < 4; j++){
      pes[j] = fmaf(acc[c][j], av, pes[j]);
      ped[j] = fmaf(acc[c][j], dv, ped[j]);
    }
  }
  #pragma unroll
  for (int off = 8; off >= 1; off >>= 1){
    #pragma unroll
    for (int j = 0; j < 4; j++){
      pes[j] += __shfl_xor(pes[j], off);
      ped[j] += __shfl_xor(ped[j], off);
    }
  }
  if (cl == 0){
    #pragma unroll
    for (int j = 0; j < 4; j++){
      int n = n0 + g*4 + j;
      es[n*4 + w] = pes[j];
      ed[n*4 + w] = ped[j];
    }
  }
  #pragma unroll
  for (int c = 0; c < 4; c++){
    #pragma unroll
    for (int j = 0; j < 4; j++){
      h[(size_t)(n0 + g*4 + j)*HC + w*64 + c*16 + cl] = f2bf(acc[c][j]);
    }
  }
}

// ---------------- GAT aggregation: 4 heads, 512B rows, 8 edges/iter (4 loads in flight) ----------------
template<int ACT>
__global__ __launch_bounds__(256) void gat_agg(const unsigned short* __restrict__ h,
    const float* __restrict__ es, const float* __restrict__ ed,
    const int* __restrict__ row_start, const int* __restrict__ csr_src,
    const float* __restrict__ bias, unsigned short* __restrict__ outp){
  __shared__ int   sbuf[4][64];
  __shared__ float wbuf[4][64][4];
  const int lane = threadIdx.x & 63;
  const int wid  = threadIdx.x >> 6;
  const int n = blockIdx.x*4 + wid;
  if (n >= N_NODES) return;
  const int rs = row_start[n], re = row_start[n+1];
  const float4 edn = *(const float4*)(ed + n*4);
  const int half = lane >> 5;
  const int l5   = lane & 31;
  const int hh   = l5 >> 3;
  const unsigned voff_lane = (unsigned)(l5 << 3);

  float4 sum4 = make_float4(0.f,0.f,0.f,0.f);
  float a0=0.f,a1=0.f,a2=0.f,a3=0.f,a4=0.f,a5=0.f,a6=0.f,a7=0.f;

  for (int base = rs; base < re; base += 64){
    const int cl = min(64, re - base);
    int e = base + lane;
    int s = (e < re) ? csr_src[e] : 0;
    float4 e4 = *(const float4*)(es + (s<<2));
    float w0 = __expf(lrelu(e4.x + edn.x));
    float w1 = __expf(lrelu(e4.y + edn.y));
    float w2 = __expf(lrelu(e4.z + edn.z));
    float w3 = __expf(lrelu(e4.w + edn.w));
    if (e >= re){ w0=0.f; w1=0.f; w2=0.f; w3=0.f; }
    sum4.x += w0; sum4.y += w1; sum4.z += w2; sum4.w += w3;
    sbuf[wid][lane] = s;
    float4 wv4; wv4.x=w0; wv4.y=w1; wv4.z=w2; wv4.w=w3;
    *(float4*)wbuf[wid][lane] = wv4;
    int j = 0;
    // main: 8 edges per iter, 4 independent 16B loads in flight per lane
    for (; j + 8 <= cl; j += 8){
      int j0 = j + half, j1 = j + 2 + half, j2 = j + 4 + half, j3 = j + 6 + half;
      float aA = wbuf[wid][j0][hh]; int sA = sbuf[wid][j0];
      float aB = wbuf[wid][j1][hh]; int sB = sbuf[wid][j1];
      float aC = wbuf[wid][j2][hh]; int sC = sbuf[wid][j2];
      float aD = wbuf[wid][j3][hh]; int sD = sbuf[wid][j3];
      uint4 hA = *(const uint4*)(h + ((unsigned)(sA<<8) + voff_lane));
      uint4 hB = *(const uint4*)(h + ((unsigned)(sB<<8) + voff_lane));
      uint4 hC = *(const uint4*)(h + ((unsigned)(sC<<8) + voff_lane));
      uint4 hD = *(const uint4*)(h + ((unsigned)(sD<<8) + voff_lane));
      a0 = fmaf(aA, bflo(hA.x), a0); a1 = fmaf(aA, bfhi(hA.x), a1);
      a2 = fmaf(aA, bflo(hA.y), a2); a3 = fmaf(aA, bfhi(hA.y), a3);
      a4 = fmaf(aA, bflo(hA.z), a4); a5 = fmaf(aA, bfhi(hA.z), a5);
      a6 = fmaf(aA, bflo(hA.w), a6); a7 = fmaf(aA, bfhi(hA.w), a7);
      a0 = fmaf(aB, bflo(hB.x), a0); a1 = fmaf(aB, bfhi(hB.x), a1);
      a2 = fmaf(aB, bflo(hB.y), a2); a3 = fmaf(aB, bfhi(hB.y), a3);
      a4 = fmaf(aB, bflo(hB.z), a4); a5 = fmaf(aB, bfhi(hB.z), a5);
      a6 = fmaf(aB, bflo(hB.w), a6); a7 = fmaf(aB, bfhi(hB.w), a7);
      a0 = fmaf(aC, bflo(hC.x), a0); a1 = fmaf(aC, bfhi(hC.x), a1);
      a2 = fmaf(aC, bflo(hC.y), a2); a3 = fmaf(aC, bfhi(hC.y), a3);
      a4 = fmaf(aC, bflo(hC.z), a4); a5 = fmaf(aC, bfhi(hC.z), a5);
      a6 = fmaf(aC, bflo(hC.w), a6); a7 = fmaf(aC, bfhi(hC.w), a7);
      a0 = fmaf(aD, bflo(hD.x), a0); a1 = fmaf(aD, bfhi(hD.x), a1);
      a2 = fmaf(aD, bflo(hD.y), a2); a3 = fmaf(aD, bfhi(hD.y), a3);
      a4 = fmaf(aD, bflo(hD.z), a4); a5 = fmaf(aD, bfhi(hD.z), a5);
      a6 = fmaf(aD, bflo(hD.w), a6); a7 = fmaf(aD, bfhi(hD.w), a7);
    }
    for (; j < cl; j += 2){
      int jj = j + half;             // jj==cl phantom safe: w=0 staged
      float a  = wbuf[wid][jj][hh];
      int   s2 = sbuf[wid][jj];
      uint4 hv = *(const uint4*)(h + ((unsigned)(s2<<8) + voff_lane));
      a0 = fmaf(a, bflo(hv.x), a0); a1 = fmaf(a, bfhi(hv.x), a1);
      a2 = fmaf(a, bflo(hv.y), a2); a3 = fmaf(a, bfhi(hv.y), a3);
      a4 = fmaf(a, bflo(hv.z), a4); a5 = fmaf(a, bfhi(hv.z), a5);
      a6 = fmaf(a, bflo(hv.w), a6); a7 = fmaf(a, bfhi(hv.w), a7);
    }
  }
  #pragma unroll
  for (int off = 32; off >= 1; off >>= 1){
    sum4.x += __shfl_xor(sum4.x, off);
    sum4.y += __shfl_xor(sum4.y, off);
    sum4.z += __shfl_xor(sum4.z, off);
    sum4.w += __shfl_xor(sum4.w, off);
  }
  const float inv = 1.f / (sel4(sum4, hh) + 1e-16f);
  a0 += __shfl_xor(a0, 32); a1 += __shfl_xor(a1, 32);
  a2 += __shfl_xor(a2, 32); a3 += __shfl_xor(a3, 32);
  a4 += __shfl_xor(a4, 32); a5 += __shfl_xor(a5, 32);
  a6 += __shfl_xor(a6, 32); a7 += __shfl_xor(a7, 32);
  float4 o;
  o.x = (half ? a4 : a0) * inv;
  o.y = (half ? a5 : a1) * inv;
  o.z = (half ? a6 : a2) * inv;
  o.w = (half ? a7 : a3) * inv;
  const int fbase = l5*8 + half*4;
  if (ACT){
    float4 b4 = *(const float4*)(bias + fbase);
    o.x += b4.x; o.y += b4.y; o.z += b4.z; o.w += b4.w;
    o.x = o.x > 0.f ? o.x : expm1f(o.x);
    o.y = o.y > 0.f ? o.y : expm1f(o.y);
    o.z = o.z > 0.f ? o.z : expm1f(o.z);
    o.w = o.w > 0.f ? o.w : expm1f(o.w);
  }
  ushort4 ob;
  ob.x = f2bf(o.x); ob.y = f2bf(o.y); ob.z = f2bf(o.z); ob.w = f2bf(o.w);
  *(ushort4*)(outp + (size_t)n*HC + fbase) = ob;
}

// ---------------- head-mean + global mean pool (bf16 input) ----------------
#define PB_NODES 64
__global__ __launch_bounds__(256) void pool_k(const unsigned short* __restrict__ xagg,
                                              const int* __restrict__ batch, float* __restrict__ pooled,
                                              float* __restrict__ cnt){
  int c = threadIdx.x & 63;
  int sub = threadIdx.x >> 6;
  int n0 = blockIdx.x * PB_NODES;
  int nend = n0 + PB_NODES; if (nend > N_NODES) nend = N_NODES;
  float acc = 0.f; int curg = -1; int cl = 0;
  for (int n = n0 + sub; n < nend; n += 4){
    int g = batch[n];
    if (g != curg){
      if (curg >= 0){
        unsafeAtomicAdd(pooled + curg*HID + c, acc);
        if (c == 0) unsafeAtomicAdd(cnt + curg, (float)cl);
      }
      curg = g; acc = 0.f; cl = 0;
    }
    const unsigned short* r = xagg + (size_t)n*HC;
    acc += 0.25f*(bf2f(r[c]) + bf2f(r[64+c]) + bf2f(r[128+c]) + bf2f(r[192+c]));
    cl++;
  }
  if (curg >= 0){
    unsafeAtomicAdd(pooled + curg*HID + c, acc);
    if (c == 0) unsafeAtomicAdd(cnt + curg, (float)cl);
  }
}

// ---------------- MLP head ----------------
__global__ __launch_bounds__(64) void mlp_k(const float* __restrict__ pooled, const float* __restrict__ cnt,
                                            const float* __restrict__ b2,
                                            const float* __restrict__ mW1, const float* __restrict__ mb1,
                                            const float* __restrict__ mW2, const float* __restrict__ mb2,
                                            float* __restrict__ out){
  __shared__ float p[HID], h1[HID];
  int g = blockIdx.x, j = threadIdx.x;
  float c = fmaxf(cnt[g], 1.f);
  p[j] = pooled[g*HID + j] / c + b2[j];
  __syncthreads();
  float acc = mb1[j];
  #pragma unroll 8
  for (int k = 0; k < HID; k++) acc = fmaf(p[k], mW1[k*HID + j], acc);
  h1[j] = fmaxf(acc, 0.f);
  __syncthreads();
  if (j < OUT_DIM){
    float a2 = mb2[j];
    #pragma unroll 8
    for (int k = 0; k < HID; k++) a2 = fmaf(h1[k], mW2[k*OUT_DIM + j], a2);
    out[g*OUT_DIM + j] = a2;
  }
}

extern "C" void kernel_launch(void* const* d_in, const int* in_sizes, int n_in,
                              void* d_out, int out_size, void* d_ws, size_t ws_size,
                              hipStream_t stream){
  const float* imgs  = (const float*)d_in[0];
  const int*   ei    = (const int*)d_in[1];
  const int*   batch = (const int*)d_in[2];
  const float* W_agg = (const float*)d_in[3];
  const float* b_agg = (const float*)d_in[4];
  const float* W0 = (const float*)d_in[5];
  const float* as0 = (const float*)d_in[6];
  const float* ad0 = (const float*)d_in[7];
  const float* b0 = (const float*)d_in[8];
  const float* W1 = (const float*)d_in[9];
  const float* as1 = (const float*)d_in[10];
  const float* ad1 = (const float*)d_in[11];
  const float* b1 = (const float*)d_in[12];
  const float* W2 = (const float*)d_in[13];
  const float* as2 = (const float*)d_in[14];
  const float* ad2 = (const float*)d_in[15];
  const float* b2 = (const float*)d_in[16];
  const float* mW1 = (const float*)d_in[17];
  const float* mb1 = (const float*)d_in[18];
  const float* mW2 = (const float*)d_in[19];
  const float* mb2 = (const float*)d_in[20];
  float* out = (float*)d_out;

  // workspace layout
  unsigned short* y4  = (unsigned short*)d_ws;                  // N*256 bf16
  unsigned short* hb  = y4 + (size_t)N_NODES*HC;                // N*256 bf16 node-major h
  unsigned short* xbf = hb + (size_t)N_NODES*HC;                // N*256 bf16 (x2 / final agg out)
  float* es   = (float*)(xbf + (size_t)N_NODES*HC);             // N*4
  float* ed   = es + (size_t)N_NODES*HEADS;                     // N*4
  float* pooled = ed + (size_t)N_NODES*HEADS;                   // 64*64
  float* cnt  = pooled + N_GRAPHS*HID;                          // 64
  float* ws0  = cnt + N_GRAPHS;                                 // 256
  float* wd0  = ws0 + 256;                                      // 256
  int* row_start = (int*)(wd0 + 256);                           // N+1
  int* csr_src   = row_start + (N_NODES+1);                     // E_TOT
  int* bucket_cursor = csr_src + E_TOT;                         // NBUK
  int* bucket_base   = bucket_cursor + NBUK;                    // NBUK
  unsigned short* WT0 = (unsigned short*)(bucket_base + NBUK);  // 256*64
  unsigned short* WT1 = WT0 + 256*64;                           // 256*256
  unsigned short* WT2 = WT1 + 256*256;                          // 256*256
  unsigned int* bucket_buf = (unsigned int*)(WT2 + 256*256);    // NBUK*CAP
  unsigned short* x0bf = (unsigned short*)bucket_buf;           // overlay: N*64 bf16 (buckets dead)

  // CSR build
  hipMemsetAsync(bucket_cursor, 0, NBUK*sizeof(int), stream);
  bin_k<<<(E_TOT + BT - 1)/BT, 256, 0, stream>>>(ei, bucket_cursor, bucket_buf);
  bucket_scan_k<<<1, 256, 0, stream>>>(bucket_cursor, bucket_base, row_start);
  build_k<<<NBUK, 256, 0, stream>>>(bucket_buf, bucket_cursor, bucket_base, row_start, csr_src);

  // fused weight prep (WT0/WT1/WT2 + ws0/wd0)
  prep_k<<<577, 256, 0, stream>>>(W0, W1, W2, as0, ad0, WT0, WT1, WT2, ws0, wd0);

  const int MB = N_NODES/16;            // 3125
  const int GB = (N_NODES + 3)/4;       // 12500

  // aggregator linear -> bf16 x0 + layer-0 scores
  agg_lin<<<GB, 256, 0, stream>>>(imgs, W_agg, b_agg, ws0, wd0, x0bf, es, ed);

  // layer 0: aggregate x0 (4-head)
  gat_agg0<<<GB, 256, 0, stream>>>(x0bf, es, ed, row_start, csr_src, y4);

  // fused: hgemm (x1) + layer-1 linear + scores
  hfuse_k<<<MB, 256, 0, stream>>>(y4, WT0, b0, WT1, as1, ad1, hb, es, ed);
  gat_agg<1><<<GB, 256, 0, stream>>>(hb, es, ed, row_start, csr_src, b1, xbf);

  // layer 2
  lin_mfma<256><<<MB, 256, 0, stream>>>(xbf, WT2, as2, ad2, hb, es, ed);
  gat_agg<0><<<GB, 256, 0, stream>>>(hb, es, ed, row_start, csr_src, nullptr, xbf);

  // pool + MLP (bf16 pool input)
  hipMemsetAsync(pooled, 0, (N_GRAPHS*HID + N_GRAPHS)*sizeof(float), stream);
  pool_k<<<(N_NODES + PB_NODES - 1)/PB_NODES, 256, 0, stream>>>(xbf, batch, pooled, cnt);
  mlp_k<<<N_GRAPHS, 64, 0, stream>>>(pooled, cnt, b2, mW1, mb1, mW2, mb2, out);
}

// Round 11
// 550.026 us; speedup vs baseline: 1.0842x; 1.0842x over previous
//
#include <hip/hip_runtime.h>
#include <hip/hip_bf16.h>

#define N_NODES 50000
#define N_EDGESX 1600000
#define E_TOT   (N_EDGESX + N_NODES)
#define IN_DIM 128
#define HID 64
#define HEADS 4
#define HC 256
#define N_GRAPHS 64
#define OUT_DIM 10
#define NEG_SLOPE 0.2f

#define NBUK 196
#define CAP 12288
#define BT 4096

typedef __attribute__((ext_vector_type(8))) short bf16x8;
typedef __attribute__((ext_vector_type(4))) float f32x4;

__device__ __forceinline__ float lrelu(float x){ return fmaxf(x, NEG_SLOPE*x); }
__device__ __forceinline__ float sel4(float4 v, int i){
  float r = v.x;
  r = (i==1) ? v.y : r;
  r = (i==2) ? v.z : r;
  r = (i==3) ? v.w : r;
  return r;
}
__device__ __forceinline__ unsigned short f2bf(float f){
  union { __hip_bfloat16 b; unsigned short u; } cv;
  cv.b = __float2bfloat16(f);
  return cv.u;
}
__device__ __forceinline__ float bf2f(unsigned short u){ return __uint_as_float(((unsigned)u) << 16); }
__device__ __forceinline__ float bflo(unsigned int u){ return __uint_as_float(u << 16); }
__device__ __forceinline__ float bfhi(unsigned int u){ return __uint_as_float(u & 0xffff0000u); }

// ---------------- CSR build: LDS-binned counting sort ----------------
__global__ __launch_bounds__(256) void bin_k(const int* __restrict__ ei,
                                             int* __restrict__ bucket_cursor,
                                             unsigned int* __restrict__ bucket_buf){
  __shared__ unsigned int pk[BT];
  __shared__ unsigned int binned[BT];
  __shared__ int hist[256], excl[256], gbase[256], lcur[256], tmp[256];
  const int tid = threadIdx.x;
  const int e0 = blockIdx.x * BT;
  const int nv = min(BT, E_TOT - e0);
  hist[tid] = 0;
  __syncthreads();
  for (int i = tid; i < nv; i += 256){
    int e = e0 + i;
    int src, dst;
    if (e < N_EDGESX){ src = ei[e]; dst = ei[N_EDGESX + e]; }
    else { src = e - N_EDGESX; dst = src; }
    pk[i] = ((unsigned)src << 16) | (unsigned)dst;
    atomicAdd(&hist[dst >> 8], 1);
  }
  __syncthreads();
  int v = hist[tid];
  tmp[tid] = v;
  __syncthreads();
  for (int off = 1; off < 256; off <<= 1){
    int t = (tid >= off) ? tmp[tid-off] : 0;
    __syncthreads();
    tmp[tid] += t;
    __syncthreads();
  }
  excl[tid] = tmp[tid] - v;
  lcur[tid] = tmp[tid] - v;
  if (tid < NBUK && v > 0) gbase[tid] = atomicAdd(&bucket_cursor[tid], v);
  __syncthreads();
  for (int i = tid; i < nv; i += 256){
    unsigned u = pk[i];
    int b = (int)((u & 0xFFFFu) >> 8);
    int p = atomicAdd(&lcur[b], 1);
    binned[p] = u;
  }
  __syncthreads();
  for (int j = tid; j < nv; j += 256){
    unsigned u = binned[j];
    int b = (int)((u & 0xFFFFu) >> 8);
    bucket_buf[(size_t)b*CAP + gbase[b] + (j - excl[b])] = u;
  }
}

__global__ __launch_bounds__(256) void bucket_scan_k(const int* __restrict__ bucket_cursor,
                                                     int* __restrict__ bucket_base,
                                                     int* __restrict__ row_start){
  __shared__ int tmp[256];
  int t = threadIdx.x;
  int v = (t < NBUK) ? bucket_cursor[t] : 0;
  tmp[t] = v;
  __syncthreads();
  for (int off = 1; off < 256; off <<= 1){
    int x = (t >= off) ? tmp[t-off] : 0;
    __syncthreads();
    tmp[t] += x;
    __syncthreads();
  }
  if (t < NBUK) bucket_base[t] = tmp[t] - v;
  if (t == 0) row_start[N_NODES] = E_TOT;
}

__global__ __launch_bounds__(256) void build_k(const unsigned int* __restrict__ bucket_buf,
                                               const int* __restrict__ bucket_cursor,
                                               const int* __restrict__ bucket_base,
                                               int* __restrict__ row_start,
                                               int* __restrict__ csr_src){
  __shared__ int hist[256], excl[256], lcur[256], tmp[256];
  const int b = blockIdx.x;
  const int t = threadIdx.x;
  const int cntb = bucket_cursor[b];
  const int base = bucket_base[b];
  const unsigned int* buf = bucket_buf + (size_t)b*CAP;
  hist[t] = 0;
  __syncthreads();
  for (int i = t; i < cntb; i += 256) atomicAdd(&hist[buf[i] & 255], 1);
  __syncthreads();
  int v = hist[t];
  tmp[t] = v;
  __syncthreads();
  for (int off = 1; off < 256; off <<= 1){
    int x = (t >= off) ? tmp[t-off] : 0;
    __syncthreads();
    tmp[t] += x;
    __syncthreads();
  }
  excl[t] = tmp[t] - v;
  lcur[t] = tmp[t] - v;
  int g = b*256 + t;
  if (g < N_NODES) row_start[g] = base + excl[t];
  __syncthreads();
  for (int i = t; i < cntb; i += 256){
    unsigned u = buf[i];
    int p = atomicAdd(&lcur[u & 255], 1);
    csr_src[base + p] = (int)(u >> 16);
  }
}

// ---------------- fused weight prep: WTa/WT0/WT1/WT2 transpose->bf16 + layer-0 projection ----------------
__global__ __launch_bounds__(256) void prep_k(const float* __restrict__ Wagg,
                                              const float* __restrict__ W0, const float* __restrict__ W1,
                                              const float* __restrict__ W2,
                                              const float* __restrict__ as0, const float* __restrict__ ad0,
                                              unsigned short* __restrict__ WTa,
                                              unsigned short* __restrict__ WT0, unsigned short* __restrict__ WT1,
                                              unsigned short* __restrict__ WT2,
                                              float* __restrict__ ws0, float* __restrict__ wd0){
  const int b = blockIdx.x, t = threadIdx.x;
  if (b < 32){
    int idx = b*256 + t;             // idx = c*128 + k ; WTa[c][k] = Wagg[k][c], [128][64]
    int c = idx >> 7, k = idx & 127;
    WTa[idx] = f2bf(Wagg[k*64 + c]);
  } else if (b < 96){
    int idx = (b-32)*256 + t;
    int k = idx >> 8, c = idx & 255;
    WT0[c*64 + k] = f2bf(W0[k*256 + c]);
  } else if (b < 352){
    int idx = (b-96)*256 + t;
    int k = idx >> 8, c = idx & 255;
    WT1[c*256 + k] = f2bf(W1[k*256 + c]);
  } else if (b < 608){
    int idx = (b-352)*256 + t;
    int k = idx >> 8, c = idx & 255;
    WT2[c*256 + k] = f2bf(W2[k*256 + c]);
  } else {
    int h = t >> 6, k = t & 63;
    float s = 0.f, d = 0.f;
    for (int c = 0; c < 64; c++){
      float wv = W0[k*256 + h*64 + c];
      s = fmaf(wv, as0[h*64 + c], s);
      d = fmaf(wv, ad0[h*64 + c], d);
    }
    ws0[t] = s; wd0[t] = d;
  }
}

// ---------------- MFMA aggregator linear: x0 = bf16(imgs@W_agg + b_agg), fused layer-0 scores ----------------
// 64 nodes/block (4 waves x 16 nodes), K=128, 64 output cols.
__global__ __launch_bounds__(256) void agg_mfma(const float* __restrict__ imgs,
                                                const unsigned short* __restrict__ WTa,
                                                const float* __restrict__ b_,
                                                const float* __restrict__ ws0, const float* __restrict__ wd0,
                                                unsigned short* __restrict__ x0,
                                                float* __restrict__ es, float* __restrict__ ed){
  __shared__ __align__(16) unsigned short xs[64][136];
  const int tid = threadIdx.x;
  const int lane = tid & 63;
  const int w = tid >> 6;
  const int n0 = blockIdx.x * 64;
  // stage imgs f32 -> bf16 LDS (64 x 128)
  for (int i = tid; i < 64*32; i += 256){
    int r = i >> 5, q = (i & 31)*4;
    int n = n0 + r;
    float4 v = (n < N_NODES) ? *(const float4*)(imgs + (size_t)n*IN_DIM + q)
                             : make_float4(0.f,0.f,0.f,0.f);
    ushort4 o; o.x = f2bf(v.x); o.y = f2bf(v.y); o.z = f2bf(v.z); o.w = f2bf(v.w);
    *(ushort4*)(&xs[r][q]) = o;
  }
  __syncthreads();
  const int g  = lane >> 4;
  const int cl = lane & 15;
  const int nb = n0 + w*16;          // this wave's node base
  f32x4 acc[4];
  #pragma unroll
  for (int c = 0; c < 4; c++) acc[c] = (f32x4){0.f,0.f,0.f,0.f};
  #pragma unroll
  for (int t = 0; t < 4; t++){
    bf16x8 a = *(const bf16x8*)(&xs[w*16 + cl][t*32 + g*8]);
    #pragma unroll
    for (int c = 0; c < 4; c++){
      bf16x8 bv = *(const bf16x8*)(WTa + (size_t)(c*16 + cl)*IN_DIM + t*32 + g*8);
      acc[c] = __builtin_amdgcn_mfma_f32_16x16x32_bf16(a, bv, acc[c], 0, 0, 0);
    }
  }
  // add bias; scores over all 4 heads (x0 is 64-dim; ws0/wd0 are [4][64])
  float pes[4][4], ped[4][4];
  #pragma unroll
  for (int h = 0; h < 4; h++)
    #pragma unroll
    for (int j = 0; j < 4; j++){ pes[h][j] = 0.f; ped[h][j] = 0.f; }
  #pragma unroll
  for (int c = 0; c < 4; c++){
    int col = c*16 + cl;
    float bb = b_[col];
    #pragma unroll
    for (int j = 0; j < 4; j++) acc[c][j] += bb;
    #pragma unroll
    for (int h = 0; h < 4; h++){
      float sv = ws0[h*64 + col];
      float dv = wd0[h*64 + col];
      #pragma unroll
      for (int j = 0; j < 4; j++){
        pes[h][j] = fmaf(acc[c][j], sv, pes[h][j]);
        ped[h][j] = fmaf(acc[c][j], dv, ped[h][j]);
      }
    }
  }
  #pragma unroll
  for (int off = 8; off >= 1; off >>= 1){
    #pragma unroll
    for (int h = 0; h < 4; h++)
      #pragma unroll
      for (int j = 0; j < 4; j++){
        pes[h][j] += __shfl_xor(pes[h][j], off);
        ped[h][j] += __shfl_xor(ped[h][j], off);
      }
  }
  if (cl == 0){
    #pragma unroll
    for (int j = 0; j < 4; j++){
      int n = nb + g*4 + j;
      if (n < N_NODES){
        float4 pv; pv.x=pes[0][j]; pv.y=pes[1][j]; pv.z=pes[2][j]; pv.w=pes[3][j];
        float4 qv; qv.x=ped[0][j]; qv.y=ped[1][j]; qv.z=ped[2][j]; qv.w=ped[3][j];
        *(float4*)(es + n*4) = pv;
        *(float4*)(ed + n*4) = qv;
      }
    }
  }
  #pragma unroll
  for (int c = 0; c < 4; c++){
    #pragma unroll
    for (int j = 0; j < 4; j++){
      int n = nb + g*4 + j;
      if (n < N_NODES) x0[(size_t)n*HID + c*16 + cl] = f2bf(acc[c][j]);
    }
  }
}

// ---------------- layer-0 aggregation: gather x0 (128B rows), 4-head weighted sums ----------------
__global__ __launch_bounds__(256) void gat_agg0(const unsigned short* __restrict__ x0,
    const float* __restrict__ es, const float* __restrict__ ed,
    const int* __restrict__ row_start, const int* __restrict__ csr_src,
    unsigned short* __restrict__ y4){
  __shared__ int   sbuf[4][64];
  __shared__ float wbuf[4][64][4];
  const int lane = threadIdx.x & 63;
  const int wid  = threadIdx.x >> 6;
  const int n = blockIdx.x*4 + wid;
  if (n >= N_NODES) return;
  const int rs = row_start[n], re = row_start[n+1];
  const float4 edn = *(const float4*)(ed + n*4);
  const int slot = lane >> 3;
  const int f8   = lane & 7;
  float4 sumw = make_float4(0.f,0.f,0.f,0.f);
  float acc[4][8];
  #pragma unroll
  for (int h=0;h<4;h++)
    #pragma unroll
    for (int q2=0;q2<8;q2++) acc[h][q2]=0.f;

  for (int base = rs; base < re; base += 64){
    const int cl = min(64, re - base);
    int e = base + lane;
    int s = (e < re) ? csr_src[e] : 0;
    float4 e4 = *(const float4*)(es + (s<<2));
    float w0 = __expf(lrelu(e4.x + edn.x));
    float w1 = __expf(lrelu(e4.y + edn.y));
    float w2 = __expf(lrelu(e4.z + edn.z));
    float w3 = __expf(lrelu(e4.w + edn.w));
    if (e >= re){ w0=0.f; w1=0.f; w2=0.f; w3=0.f; }
    sumw.x += w0; sumw.y += w1; sumw.z += w2; sumw.w += w3;
    sbuf[wid][lane] = s;
    float4 wv; wv.x=w0; wv.y=w1; wv.z=w2; wv.w=w3;
    *(float4*)wbuf[wid][lane] = wv;
    int j = 0;
    for (; j + 16 <= cl; j += 16){
      int j0 = j + slot, j1 = j + 8 + slot;
      float4 awA = *(const float4*)wbuf[wid][j0]; int sA = sbuf[wid][j0];
      float4 awB = *(const float4*)wbuf[wid][j1]; int sB = sbuf[wid][j1];
      uint4 hvA = *(const uint4*)(x0 + ((unsigned)(sA<<6) + (unsigned)(f8<<3)));
      uint4 hvB = *(const uint4*)(x0 + ((unsigned)(sB<<6) + (unsigned)(f8<<3)));
      float fA[8] = {bflo(hvA.x),bfhi(hvA.x),bflo(hvA.y),bfhi(hvA.y),
                     bflo(hvA.z),bfhi(hvA.z),bflo(hvA.w),bfhi(hvA.w)};
      float fB[8] = {bflo(hvB.x),bfhi(hvB.x),bflo(hvB.y),bfhi(hvB.y),
                     bflo(hvB.z),bfhi(hvB.z),bflo(hvB.w),bfhi(hvB.w)};
      #pragma unroll
      for (int q2=0;q2<8;q2++){
        acc[0][q2] = fmaf(awA.x, fA[q2], acc[0][q2]);
        acc[1][q2] = fmaf(awA.y, fA[q2], acc[1][q2]);
        acc[2][q2] = fmaf(awA.z, fA[q2], acc[2][q2]);
        acc[3][q2] = fmaf(awA.w, fA[q2], acc[3][q2]);
      }
      #pragma unroll
      for (int q2=0;q2<8;q2++){
        acc[0][q2] = fmaf(awB.x, fB[q2], acc[0][q2]);
        acc[1][q2] = fmaf(awB.y, fB[q2], acc[1][q2]);
        acc[2][q2] = fmaf(awB.z, fB[q2], acc[2][q2]);
        acc[3][q2] = fmaf(awB.w, fB[q2], acc[3][q2]);
      }
    }
    for (; j < cl; j += 8){
      int jj = j + slot;
      if (jj < cl){
        float4 aw = *(const float4*)wbuf[wid][jj];
        int s2 = sbuf[wid][jj];
        uint4 hv = *(const uint4*)(x0 + ((unsigned)(s2<<6) + (unsigned)(f8<<3)));
        float f[8] = {bflo(hv.x),bfhi(hv.x),bflo(hv.y),bfhi(hv.y),
                      bflo(hv.z),bfhi(hv.z),bflo(hv.w),bfhi(hv.w)};
        #pragma unroll
        for (int q2=0;q2<8;q2++){
          acc[0][q2] = fmaf(aw.x, f[q2], acc[0][q2]);
          acc[1][q2] = fmaf(aw.y, f[q2], acc[1][q2]);
          acc[2][q2] = fmaf(aw.z, f[q2], acc[2][q2]);
          acc[3][q2] = fmaf(aw.w, f[q2], acc[3][q2]);
        }
      }
    }
  }
  #pragma unroll
  for (int off = 8; off <= 32; off <<= 1){
    #pragma unroll
    for (int h=0;h<4;h++)
      #pragma unroll
      for (int q2=0;q2<8;q2++) acc[h][q2] += __shfl_xor(acc[h][q2], off);
  }
  #pragma unroll
  for (int off = 32; off >= 1; off >>= 1){
    sumw.x += __shfl_xor(sumw.x, off);
    sumw.y += __shfl_xor(sumw.y, off);
    sumw.z += __shfl_xor(sumw.z, off);
    sumw.w += __shfl_xor(sumw.w, off);
  }
  if (lane < 32){
    int h = lane >> 3;
    float inv = 1.f / (sel4(sumw, h) + 1e-16f);
    union { unsigned short u[8]; uint4 v; } ob;
    #pragma unroll
    for (int q2=0;q2<8;q2++) ob.u[q2] = f2bf(acc[h][q2] * inv);
    *(uint4*)(y4 + (size_t)n*HC + lane*8) = ob.v;
  }
}

// ---------------- fused: x1 = ELU(y4@W0_bd + b0) in LDS, then h1 = x1@W1 + scores ----------------
__global__ __launch_bounds__(256) void hfuse_k(const unsigned short* __restrict__ y4,
                                               const unsigned short* __restrict__ WT0,
                                               const float* __restrict__ b0,
                                               const unsigned short* __restrict__ WT1,
                                               const float* __restrict__ as_, const float* __restrict__ ad_,
                                               unsigned short* __restrict__ h,
                                               float* __restrict__ es, float* __restrict__ ed){
  __shared__ __align__(16) unsigned short xs[16][264];
  __shared__ __align__(16) unsigned short x1s[16][264];
  const int tid = threadIdx.x;
  const int lane = tid & 63;
  const int w = tid >> 6;
  const int n0 = blockIdx.x * 16;
  for (int i = tid; i < 16*32; i += 256){
    int r = i >> 5, cc = (i & 31) * 8;
    *(uint4*)(&xs[r][cc]) = *(const uint4*)(y4 + (size_t)(n0+r)*HC + cc);
  }
  __syncthreads();
  const int g = lane >> 4, cl = lane & 15;
  {
    f32x4 acc[4];
    #pragma unroll
    for (int c = 0; c < 4; c++) acc[c] = (f32x4){0.f,0.f,0.f,0.f};
    #pragma unroll
    for (int t = 0; t < 2; t++){
      bf16x8 a = *(const bf16x8*)(&xs[cl][w*64 + t*32 + g*8]);
      #pragma unroll
      for (int c = 0; c < 4; c++){
        bf16x8 bv = *(const bf16x8*)(WT0 + (size_t)(w*64 + c*16 + cl)*64 + t*32 + g*8);
        acc[c] = __builtin_amdgcn_mfma_f32_16x16x32_bf16(a, bv, acc[c], 0, 0, 0);
      }
    }
    #pragma unroll
    for (int c = 0; c < 4; c++){
      int col = w*64 + c*16 + cl;
      float bb = b0[col];
      #pragma unroll
      for (int j = 0; j < 4; j++){
        float v = acc[c][j] + bb;
        v = v > 0.f ? v : expm1f(v);
        x1s[g*4 + j][col] = f2bf(v);
      }
    }
  }
  __syncthreads();
  f32x4 acc[4];
  #pragma unroll
  for (int c = 0; c < 4; c++) acc[c] = (f32x4){0.f,0.f,0.f,0.f};
  #pragma unroll
  for (int t = 0; t < 8; t++){
    bf16x8 a = *(const bf16x8*)(&x1s[cl][t*32 + g*8]);
    #pragma unroll
    for (int c = 0; c < 4; c++){
      bf16x8 bv = *(const bf16x8*)(WT1 + (size_t)(w*64 + c*16 + cl)*HC + t*32 + g*8);
      acc[c] = __builtin_amdgcn_mfma_f32_16x16x32_bf16(a, bv, acc[c], 0, 0, 0);
    }
  }
  float pes[4] = {0.f,0.f,0.f,0.f}, ped[4] = {0.f,0.f,0.f,0.f};
  #pragma unroll
  for (int c = 0; c < 4; c++){
    float av = as_[w*64 + c*16 + cl];
    float dv = ad_[w*64 + c*16 + cl];
    #pragma unroll
    for (int j = 0; j < 4; j++){
      pes[j] = fmaf(acc[c][j], av, pes[j]);
      ped[j] = fmaf(acc[c][j], dv, ped[j]);
    }
  }
  #pragma unroll
  for (int off = 8; off >= 1; off >>= 1){
    #pragma unroll
    for (int j = 0; j < 4; j++){
      pes[j] += __shfl_xor(pes[j], off);
      ped[j] += __shfl_xor(ped[j], off);
    }
  }
  if (cl == 0){
    #pragma unroll
    for (int j = 0; j < 4; j++){
      int n = n0 + g*4 + j;
      es[n*4 + w] = pes[j];
      ed[n*4 + w] = ped[j];
    }
  }
  #pragma unroll
  for (int c = 0; c < 4; c++){
    #pragma unroll
    for (int j = 0; j < 4; j++){
      h[(size_t)(n0 + g*4 + j)*HC + w*64 + c*16 + cl] = f2bf(acc[c][j]);
    }
  }
}

// ---------------- MFMA GAT linear + fused scores; h NODE-major [N,256] ----------------
template<int K>
__global__ __launch_bounds__(256) void lin_mfma(const unsigned short* __restrict__ x,
                                                const unsigned short* __restrict__ WT,
                                                const float* __restrict__ as_, const float* __restrict__ ad_,
                                                unsigned short* __restrict__ h,
                                                float* __restrict__ es, float* __restrict__ ed){
  constexpr int KP = K + 8;
  __shared__ __align__(16) unsigned short xs[16][KP];
  const int tid = threadIdx.x;
  const int lane = tid & 63;
  const int w = tid >> 6;
  const int n0 = blockIdx.x * 16;
  constexpr int CH = K/8;
  for (int i = tid; i < 16*CH; i += 256){
    int r = i / CH, cc = (i % CH)*8;
    *(uint4*)(&xs[r][cc]) = *(const uint4*)(x + (size_t)(n0+r)*K + cc);
  }
  __syncthreads();
  const int g  = lane >> 4;
  const int cl = lane & 15;
  f32x4 acc[4];
  #pragma unroll
  for (int c = 0; c < 4; c++) acc[c] = (f32x4){0.f,0.f,0.f,0.f};
  #pragma unroll
  for (int t = 0; t < K/32; t++){
    bf16x8 a = *(const bf16x8*)(&xs[cl][t*32 + g*8]);
    #pragma unroll
    for (int c = 0; c < 4; c++){
      bf16x8 bv = *(const bf16x8*)(WT + (size_t)(w*64 + c*16 + cl)*K + t*32 + g*8);
      acc[c] = __builtin_amdgcn_mfma_f32_16x16x32_bf16(a, bv, acc[c], 0, 0, 0);
    }
  }
  float pes[4] = {0.f,0.f,0.f,0.f}, ped[4] = {0.f,0.f,0.f,0.f};
  #pragma unroll
  for (int c = 0; c < 4; c++){
    float av = as_[w*64 + c*16 + cl];
    float dv = ad_[w*64 + c*16 + cl];
    #pragma unroll
    for (int j = 0; j < 4; j++){
      pes[j] = fmaf(acc[c][j], av, pes[j]);
      ped[j] = fmaf(acc[c][j], dv, ped[j]);
    }
  }
  #pragma unroll
  for (int off = 8; off >= 1; off >>= 1){
    #pragma unroll
    for (int j = 0; j < 4; j++){
      pes[j] += __shfl_xor(pes[j], off);
      ped[j] += __shfl_xor(ped[j], off);
    }
  }
  if (cl == 0){
    #pragma unroll
    for (int j = 0; j < 4; j++){
      int n = n0 + g*4 + j;
      es[n*4 + w] = pes[j];
      ed[n*4 + w] = ped[j];
    }
  }
  #pragma unroll
  for (int c = 0; c < 4; c++){
    #pragma unroll
    for (int j = 0; j < 4; j++){
      h[(size_t)(n0 + g*4 + j)*HC + w*64 + c*16 + cl] = f2bf(acc[c][j]);
    }
  }
}

// ---------------- GAT aggregation: 4 heads, 512B rows, 8 edges/iter ----------------
// OUT64: write 64-dim head-mean (bf16) instead of full 256-dim output
template<int ACT, int OUT64>
__global__ __launch_bounds__(256) void gat_agg(const unsigned short* __restrict__ h,
    const float* __restrict__ es, const float* __restrict__ ed,
    const int* __restrict__ row_start, const int* __restrict__ csr_src,
    const float* __restrict__ bias, unsigned short* __restrict__ outp){
  __shared__ int   sbuf[4][64];
  __shared__ float wbuf[4][64][4];
  const int lane = threadIdx.x & 63;
  const int wid  = threadIdx.x >> 6;
  const int n = blockIdx.x*4 + wid;
  if (n >= N_NODES) return;
  const int rs = row_start[n], re = row_start[n+1];
  const float4 edn = *(const float4*)(ed + n*4);
  const int half = lane >> 5;
  const int l5   = lane & 31;
  const int hh   = l5 >> 3;
  const unsigned voff_lane = (unsigned)(l5 << 3);

  float4 sum4 = make_float4(0.f,0.f,0.f,0.f);
  float a0=0.f,a1=0.f,a2=0.f,a3=0.f,a4=0.f,a5=0.f,a6=0.f,a7=0.f;

  for (int base = rs; base < re; base += 64){
    const int cl = min(64, re - base);
    int e = base + lane;
    int s = (e < re) ? csr_src[e] : 0;
    float4 e4 = *(const float4*)(es + (s<<2));
    float w0 = __expf(lrelu(e4.x + edn.x));
    float w1 = __expf(lrelu(e4.y + edn.y));
    float w2 = __expf(lrelu(e4.z + edn.z));
    float w3 = __expf(lrelu(e4.w + edn.w));
    if (e >= re){ w0=0.f; w1=0.f; w2=0.f; w3=0.f; }
    sum4.x += w0; sum4.y += w1; sum4.z += w2; sum4.w += w3;
    sbuf[wid][lane] = s;
    float4 wv4; wv4.x=w0; wv4.y=w1; wv4.z=w2; wv4.w=w3;
    *(float4*)wbuf[wid][lane] = wv4;
    int j = 0;
    for (; j + 8 <= cl; j += 8){
      int j0 = j + half, j1 = j + 2 + half, j2 = j + 4 + half, j3 = j + 6 + half;
      float aA = wbuf[wid][j0][hh]; int sA = sbuf[wid][j0];
      float aB = wbuf[wid][j1][hh]; int sB = sbuf[wid][j1];
      float aC = wbuf[wid][j2][hh]; int sC = sbuf[wid][j2];
      float aD = wbuf[wid][j3][hh]; int sD = sbuf[wid][j3];
      uint4 hA = *(const uint4*)(h + ((unsigned)(sA<<8) + voff_lane));
      uint4 hB = *(const uint4*)(h + ((unsigned)(sB<<8) + voff_lane));
      uint4 hC = *(const uint4*)(h + ((unsigned)(sC<<8) + voff_lane));
      uint4 hD = *(const uint4*)(h + ((unsigned)(sD<<8) + voff_lane));
      a0 = fmaf(aA, bflo(hA.x), a0); a1 = fmaf(aA, bfhi(hA.x), a1);
      a2 = fmaf(aA, bflo(hA.y), a2); a3 = fmaf(aA, bfhi(hA.y), a3);
      a4 = fmaf(aA, bflo(hA.z), a4); a5 = fmaf(aA, bfhi(hA.z), a5);
      a6 = fmaf(aA, bflo(hA.w), a6); a7 = fmaf(aA, bfhi(hA.w), a7);
      a0 = fmaf(aB, bflo(hB.x), a0); a1 = fmaf(aB, bfhi(hB.x), a1);
      a2 = fmaf(aB, bflo(hB.y), a2); a3 = fmaf(aB, bfhi(hB.y), a3);
      a4 = fmaf(aB, bflo(hB.z), a4); a5 = fmaf(aB, bfhi(hB.z), a5);
      a6 = fmaf(aB, bflo(hB.w), a6); a7 = fmaf(aB, bfhi(hB.w), a7);
      a0 = fmaf(aC, bflo(hC.x), a0); a1 = fmaf(aC, bfhi(hC.x), a1);
      a2 = fmaf(aC, bflo(hC.y), a2); a3 = fmaf(aC, bfhi(hC.y), a3);
      a4 = fmaf(aC, bflo(hC.z), a4); a5 = fmaf(aC, bfhi(hC.z), a5);
      a6 = fmaf(aC, bflo(hC.w), a6); a7 = fmaf(aC, bfhi(hC.w), a7);
      a0 = fmaf(aD, bflo(hD.x), a0); a1 = fmaf(aD, bfhi(hD.x), a1);
      a2 = fmaf(aD, bflo(hD.y), a2); a3 = fmaf(aD, bfhi(hD.y), a3);
      a4 = fmaf(aD, bflo(hD.z), a4); a5 = fmaf(aD, bfhi(hD.z), a5);
      a6 = fmaf(aD, bflo(hD.w), a6); a7 = fmaf(aD, bfhi(hD.w), a7);
    }
    for (; j < cl; j += 2){
      int jj = j + half;
      float a  = wbuf[wid][jj][hh];
      int   s2 = sbuf[wid][jj];
      uint4 hv = *(const uint4*)(h + ((unsigned)(s2<<8) + voff_lane));
      a0 = fmaf(a, bflo(hv.x), a0); a1 = fmaf(a, bfhi(hv.x), a1);
      a2 = fmaf(a, bflo(hv.y), a2); a3 = fmaf(a, bfhi(hv.y), a3);
      a4 = fmaf(a, bflo(hv.z), a4); a5 = fmaf(a, bfhi(hv.z), a5);
      a6 = fmaf(a, bflo(hv.w), a6); a7 = fmaf(a, bfhi(hv.w), a7);
    }
  }
  #pragma unroll
  for (int off = 32; off >= 1; off >>= 1){
    sum4.x += __shfl_xor(sum4.x, off);
    sum4.y += __shfl_xor(sum4.y, off);
    sum4.z += __shfl_xor(sum4.z, off);
    sum4.w += __shfl_xor(sum4.w, off);
  }
  const float inv = 1.f / (sel4(sum4, hh) + 1e-16f);
  a0 += __shfl_xor(a0, 32); a1 += __shfl_xor(a1, 32);
  a2 += __shfl_xor(a2, 32); a3 += __shfl_xor(a3, 32);
  a4 += __shfl_xor(a4, 32); a5 += __shfl_xor(a5, 32);
  a6 += __shfl_xor(a6, 32); a7 += __shfl_xor(a7, 32);
  float4 o;
  o.x = (half ? a4 : a0) * inv;
  o.y = (half ? a5 : a1) * inv;
  o.z = (half ? a6 : a2) * inv;
  o.w = (half ? a7 : a3) * inv;
  if (ACT){
    const int fbase = l5*8 + half*4;
    float4 b4 = *(const float4*)(bias + fbase);
    o.x += b4.x; o.y += b4.y; o.z += b4.z; o.w += b4.w;
    o.x = o.x > 0.f ? o.x : expm1f(o.x);
    o.y = o.y > 0.f ? o.y : expm1f(o.y);
    o.z = o.z > 0.f ? o.z : expm1f(o.z);
    o.w = o.w > 0.f ? o.w : expm1f(o.w);
  }
  if (OUT64){
    // head-mean: sum over l5 bits 3,4 (lanes ^8, ^16), x0.25
    o.x += __shfl_xor(o.x, 8); o.y += __shfl_xor(o.y, 8);
    o.z += __shfl_xor(o.z, 8); o.w += __shfl_xor(o.w, 8);
    o.x += __shfl_xor(o.x, 16); o.y += __shfl_xor(o.y, 16);
    o.z += __shfl_xor(o.z, 16); o.w += __shfl_xor(o.w, 16);
    if (l5 < 8){
      ushort4 ob;
      ob.x = f2bf(0.25f*o.x); ob.y = f2bf(0.25f*o.y);
      ob.z = f2bf(0.25f*o.z); ob.w = f2bf(0.25f*o.w);
      *(ushort4*)(outp + (size_t)n*HID + l5*8 + half*4) = ob;
    }
  } else {
    const int fbase = l5*8 + half*4;
    ushort4 ob;
    ob.x = f2bf(o.x); ob.y = f2bf(o.y); ob.z = f2bf(o.z); ob.w = f2bf(o.w);
    *(ushort4*)(outp + (size_t)n*HC + fbase) = ob;
  }
}

// ---------------- global mean pool (bf16 64-dim input) ----------------
#define PB_NODES 64
__global__ __launch_bounds__(256) void pool_k(const unsigned short* __restrict__ x64,
                                              const int* __restrict__ batch, float* __restrict__ pooled,
                                              float* __restrict__ cnt){
  int c = threadIdx.x & 63;
  int sub = threadIdx.x >> 6;
  int n0 = blockIdx.x * PB_NODES;
  int nend = n0 + PB_NODES; if (nend > N_NODES) nend = N_NODES;
  float acc = 0.f; int curg = -1; int cl = 0;
  for (int n = n0 + sub; n < nend; n += 4){
    int g = batch[n];
    if (g != curg){
      if (curg >= 0){
        unsafeAtomicAdd(pooled + curg*HID + c, acc);
        if (c == 0) unsafeAtomicAdd(cnt + curg, (float)cl);
      }
      curg = g; acc = 0.f; cl = 0;
    }
    acc += bf2f(x64[(size_t)n*HID + c]);
    cl++;
  }
  if (curg >= 0){
    unsafeAtomicAdd(pooled + curg*HID + c, acc);
    if (c == 0) unsafeAtomicAdd(cnt + curg, (float)cl);
  }
}

// ---------------- MLP head ----------------
__global__ __launch_bounds__(64) void mlp_k(const float* __restrict__ pooled, const float* __restrict__ cnt,
                                            const float* __restrict__ b2,
                                            const float* __restrict__ mW1, const float* __restrict__ mb1,
                                            const float* __restrict__ mW2, const float* __restrict__ mb2,
                                            float* __restrict__ out){
  __shared__ float p[HID], h1[HID];
  int g = blockIdx.x, j = threadIdx.x;
  float c = fmaxf(cnt[g], 1.f);
  p[j] = pooled[g*HID + j] / c + b2[j];
  __syncthreads();
  float acc = mb1[j];
  #pragma unroll 8
  for (int k = 0; k < HID; k++) acc = fmaf(p[k], mW1[k*HID + j], acc);
  h1[j] = fmaxf(acc, 0.f);
  __syncthreads();
  if (j < OUT_DIM){
    float a2 = mb2[j];
    #pragma unroll 8
    for (int k = 0; k < HID; k++) a2 = fmaf(h1[k], mW2[k*OUT_DIM + j], a2);
    out[g*OUT_DIM + j] = a2;
  }
}

extern "C" void kernel_launch(void* const* d_in, const int* in_sizes, int n_in,
                              void* d_out, int out_size, void* d_ws, size_t ws_size,
                              hipStream_t stream){
  const float* imgs  = (const float*)d_in[0];
  const int*   ei    = (const int*)d_in[1];
  const int*   batch = (const int*)d_in[2];
  const float* W_agg = (const float*)d_in[3];
  const float* b_agg = (const float*)d_in[4];
  const float* W0 = (const float*)d_in[5];
  const float* as0 = (const float*)d_in[6];
  const float* ad0 = (const float*)d_in[7];
  const float* b0 = (const float*)d_in[8];
  const float* W1 = (const float*)d_in[9];
  const float* as1 = (const float*)d_in[10];
  const float* ad1 = (const float*)d_in[11];
  const float* b1 = (const float*)d_in[12];
  const float* W2 = (const float*)d_in[13];
  const float* as2 = (const float*)d_in[14];
  const float* ad2 = (const float*)d_in[15];
  const float* b2 = (const float*)d_in[16];
  const float* mW1 = (const float*)d_in[17];
  const float* mb1 = (const float*)d_in[18];
  const float* mW2 = (const float*)d_in[19];
  const float* mb2 = (const float*)d_in[20];
  float* out = (float*)d_out;

  // workspace layout
  unsigned short* y4  = (unsigned short*)d_ws;                  // N*256 bf16
  unsigned short* hb  = y4 + (size_t)N_NODES*HC;                // N*256 bf16 node-major h
  unsigned short* xbf = hb + (size_t)N_NODES*HC;                // N*256 bf16 (x2) / N*64 (head-mean out)
  float* es   = (float*)(xbf + (size_t)N_NODES*HC);             // N*4
  float* ed   = es + (size_t)N_NODES*HEADS;                     // N*4
  float* pooled = ed + (size_t)N_NODES*HEADS;                   // 64*64
  float* cnt  = pooled + N_GRAPHS*HID;                          // 64
  float* ws0  = cnt + N_GRAPHS;                                 // 256
  float* wd0  = ws0 + 256;                                      // 256
  int* row_start = (int*)(wd0 + 256);                           // N+1
  int* csr_src   = row_start + (N_NODES+1);                     // E_TOT
  int* bucket_cursor = csr_src + E_TOT;                         // NBUK
  int* bucket_base   = bucket_cursor + NBUK;                    // NBUK
  unsigned short* WTa = (unsigned short*)(bucket_base + NBUK);  // 64*128
  unsigned short* WT0 = WTa + 64*128;                           // 256*64
  unsigned short* WT1 = WT0 + 256*64;                           // 256*256
  unsigned short* WT2 = WT1 + 256*256;                          // 256*256
  unsigned int* bucket_buf = (unsigned int*)(WT2 + 256*256);    // NBUK*CAP
  unsigned short* x0bf = (unsigned short*)bucket_buf;           // overlay: N*64 bf16 (buckets dead)

  // CSR build
  hipMemsetAsync(bucket_cursor, 0, NBUK*sizeof(int), stream);
  bin_k<<<(E_TOT + BT - 1)/BT, 256, 0, stream>>>(ei, bucket_cursor, bucket_buf);
  bucket_scan_k<<<1, 256, 0, stream>>>(bucket_cursor, bucket_base, row_start);
  build_k<<<NBUK, 256, 0, stream>>>(bucket_buf, bucket_cursor, bucket_base, row_start, csr_src);

  // fused weight prep (WTa/WT0/WT1/WT2 + ws0/wd0)
  prep_k<<<609, 256, 0, stream>>>(W_agg, W0, W1, W2, as0, ad0, WTa, WT0, WT1, WT2, ws0, wd0);

  const int MB = N_NODES/16;            // 3125
  const int GB = (N_NODES + 3)/4;       // 12500
  const int AB = (N_NODES + 63)/64;     // 782

  // MFMA aggregator linear -> bf16 x0 + layer-0 scores
  agg_mfma<<<AB, 256, 0, stream>>>(imgs, WTa, b_agg, ws0, wd0, x0bf, es, ed);

  // layer 0: aggregate x0 (4-head)
  gat_agg0<<<GB, 256, 0, stream>>>(x0bf, es, ed, row_start, csr_src, y4);

  // fused: hgemm (x1) + layer-1 linear + scores
  hfuse_k<<<MB, 256, 0, stream>>>(y4, WT0, b0, WT1, as1, ad1, hb, es, ed);
  gat_agg<1,0><<<GB, 256, 0, stream>>>(hb, es, ed, row_start, csr_src, b1, xbf);

  // layer 2
  lin_mfma<256><<<MB, 256, 0, stream>>>(xbf, WT2, as2, ad2, hb, es, ed);
  gat_agg<0,1><<<GB, 256, 0, stream>>>(hb, es, ed, row_start, csr_src, nullptr, xbf);

  // pool + MLP (bf16 64-dim pool input)
  hipMemsetAsync(pooled, 0, (N_GRAPHS*HID + N_GRAPHS)*sizeof(float), stream);
  pool_k<<<(N_NODES + PB_NODES - 1)/PB_NODES, 256, 0, stream>>>(xbf, batch, pooled, cnt);
  mlp_k<<<N_GRAPHS, 64, 0, stream>>>(pooled, cnt, b2, mW1, mb1, mW2, mb2, out);
}

// Round 12
// 544.853 us; speedup vs baseline: 1.0945x; 1.0095x over previous
//
#include <hip/hip_runtime.h>
#include <hip/hip_bf16.h>

#define N_NODES 50000
#define N_EDGESX 1600000
#define E_TOT   (N_EDGESX + N_NODES)
#define IN_DIM 128
#define HID 64
#define HEADS 4
#define HC 256
#define N_GRAPHS 64
#define OUT_DIM 10
#define NEG_SLOPE 0.2f

#define NBUK 196
#define CAP 12288
#define BT 4096

typedef __attribute__((ext_vector_type(8))) short bf16x8;
typedef __attribute__((ext_vector_type(4))) float f32x4;

__device__ __forceinline__ float lrelu(float x){ return fmaxf(x, NEG_SLOPE*x); }
__device__ __forceinline__ float sel4(float4 v, int i){
  float r = v.x;
  r = (i==1) ? v.y : r;
  r = (i==2) ? v.z : r;
  r = (i==3) ? v.w : r;
  return r;
}
__device__ __forceinline__ unsigned short f2bf(float f){
  union { __hip_bfloat16 b; unsigned short u; } cv;
  cv.b = __float2bfloat16(f);
  return cv.u;
}
__device__ __forceinline__ float bf2f(unsigned short u){ return __uint_as_float(((unsigned)u) << 16); }
__device__ __forceinline__ float bflo(unsigned int u){ return __uint_as_float(u << 16); }
__device__ __forceinline__ float bfhi(unsigned int u){ return __uint_as_float(u & 0xffff0000u); }

// ---------------- CSR build: LDS-binned counting sort ----------------
__global__ __launch_bounds__(256) void bin_k(const int* __restrict__ ei,
                                             int* __restrict__ bucket_cursor,
                                             unsigned int* __restrict__ bucket_buf){
  __shared__ unsigned int pk[BT];
  __shared__ unsigned int binned[BT];
  __shared__ int hist[256], excl[256], gbase[256], lcur[256], tmp[256];
  const int tid = threadIdx.x;
  const int e0 = blockIdx.x * BT;
  const int nv = min(BT, E_TOT - e0);
  hist[tid] = 0;
  __syncthreads();
  for (int i = tid; i < nv; i += 256){
    int e = e0 + i;
    int src, dst;
    if (e < N_EDGESX){ src = ei[e]; dst = ei[N_EDGESX + e]; }
    else { src = e - N_EDGESX; dst = src; }
    pk[i] = ((unsigned)src << 16) | (unsigned)dst;
    atomicAdd(&hist[dst >> 8], 1);
  }
  __syncthreads();
  int v = hist[tid];
  tmp[tid] = v;
  __syncthreads();
  for (int off = 1; off < 256; off <<= 1){
    int t = (tid >= off) ? tmp[tid-off] : 0;
    __syncthreads();
    tmp[tid] += t;
    __syncthreads();
  }
  excl[tid] = tmp[tid] - v;
  lcur[tid] = tmp[tid] - v;
  if (tid < NBUK && v > 0) gbase[tid] = atomicAdd(&bucket_cursor[tid], v);
  __syncthreads();
  for (int i = tid; i < nv; i += 256){
    unsigned u = pk[i];
    int b = (int)((u & 0xFFFFu) >> 8);
    int p = atomicAdd(&lcur[b], 1);
    binned[p] = u;
  }
  __syncthreads();
  for (int j = tid; j < nv; j += 256){
    unsigned u = binned[j];
    int b = (int)((u & 0xFFFFu) >> 8);
    bucket_buf[(size_t)b*CAP + gbase[b] + (j - excl[b])] = u;
  }
}

// build_k v2: integrates the bucket-count scan (each block redundantly scans 196 counts)
__global__ __launch_bounds__(256) void build_k(const unsigned int* __restrict__ bucket_buf,
                                               const int* __restrict__ bucket_cursor,
                                               int* __restrict__ row_start,
                                               int* __restrict__ csr_src){
  __shared__ int hist[256], excl[256], lcur[256], tmp[256];
  __shared__ int bbase;
  const int b = blockIdx.x;
  const int t = threadIdx.x;
  // scan bucket counts to find this bucket's global base
  int bc = (t < NBUK) ? bucket_cursor[t] : 0;
  tmp[t] = bc;
  __syncthreads();
  for (int off = 1; off < 256; off <<= 1){
    int x = (t >= off) ? tmp[t-off] : 0;
    __syncthreads();
    tmp[t] += x;
    __syncthreads();
  }
  if (t == b) bbase = tmp[t] - bc;      // exclusive prefix at bucket b
  if (b == 0 && t == 0) row_start[N_NODES] = E_TOT;
  __syncthreads();
  const int cntb = bucket_cursor[b];
  const int base = bbase;
  const unsigned int* buf = bucket_buf + (size_t)b*CAP;
  hist[t] = 0;
  __syncthreads();
  for (int i = t; i < cntb; i += 256) atomicAdd(&hist[buf[i] & 255], 1);
  __syncthreads();
  int v = hist[t];
  tmp[t] = v;
  __syncthreads();
  for (int off = 1; off < 256; off <<= 1){
    int x = (t >= off) ? tmp[t-off] : 0;
    __syncthreads();
    tmp[t] += x;
    __syncthreads();
  }
  excl[t] = tmp[t] - v;
  lcur[t] = tmp[t] - v;
  int g = b*256 + t;
  if (g < N_NODES) row_start[g] = base + excl[t];
  __syncthreads();
  for (int i = t; i < cntb; i += 256){
    unsigned u = buf[i];
    int p = atomicAdd(&lcur[u & 255], 1);
    csr_src[base + p] = (int)(u >> 16);
  }
}

// ---------------- fused weight prep + pooled zeroing ----------------
__global__ __launch_bounds__(256) void prep_k(const float* __restrict__ Wagg,
                                              const float* __restrict__ W0, const float* __restrict__ W1,
                                              const float* __restrict__ W2,
                                              const float* __restrict__ as0, const float* __restrict__ ad0,
                                              unsigned short* __restrict__ WTa,
                                              unsigned short* __restrict__ WT0, unsigned short* __restrict__ WT1,
                                              unsigned short* __restrict__ WT2,
                                              float* __restrict__ ws0, float* __restrict__ wd0,
                                              float* __restrict__ pooled){
  const int b = blockIdx.x, t = threadIdx.x;
  if (b < 32){
    int idx = b*256 + t;             // WTa[c][k] = Wagg[k][c], [64][128]
    int c = idx >> 7, k = idx & 127;
    WTa[idx] = f2bf(Wagg[k*64 + c]);
  } else if (b < 96){
    int idx = (b-32)*256 + t;
    int k = idx >> 8, c = idx & 255;
    WT0[c*64 + k] = f2bf(W0[k*256 + c]);
  } else if (b < 352){
    int idx = (b-96)*256 + t;
    int k = idx >> 8, c = idx & 255;
    WT1[c*256 + k] = f2bf(W1[k*256 + c]);
  } else if (b < 608){
    int idx = (b-352)*256 + t;
    int k = idx >> 8, c = idx & 255;
    WT2[c*256 + k] = f2bf(W2[k*256 + c]);
  } else {
    int h = t >> 6, k = t & 63;
    float s = 0.f, d = 0.f;
    for (int c = 0; c < 64; c++){
      float wv = W0[k*256 + h*64 + c];
      s = fmaf(wv, as0[h*64 + c], s);
      d = fmaf(wv, ad0[h*64 + c], d);
    }
    ws0[t] = s; wd0[t] = d;
    // zero pooled (4096) + cnt (64), contiguous
    for (int i = t; i < N_GRAPHS*HID + N_GRAPHS; i += 256) pooled[i] = 0.f;
  }
}

// ---------------- MFMA aggregator linear: x0 = bf16(imgs@W_agg + b_agg), fused layer-0 scores ----------------
__global__ __launch_bounds__(256) void agg_mfma(const float* __restrict__ imgs,
                                                const unsigned short* __restrict__ WTa,
                                                const float* __restrict__ b_,
                                                const float* __restrict__ ws0, const float* __restrict__ wd0,
                                                unsigned short* __restrict__ x0,
                                                float* __restrict__ es, float* __restrict__ ed){
  __shared__ __align__(16) unsigned short xs[64][136];
  const int tid = threadIdx.x;
  const int lane = tid & 63;
  const int w = tid >> 6;
  const int n0 = blockIdx.x * 64;
  for (int i = tid; i < 64*32; i += 256){
    int r = i >> 5, q = (i & 31)*4;
    int n = n0 + r;
    float4 v = (n < N_NODES) ? *(const float4*)(imgs + (size_t)n*IN_DIM + q)
                             : make_float4(0.f,0.f,0.f,0.f);
    ushort4 o; o.x = f2bf(v.x); o.y = f2bf(v.y); o.z = f2bf(v.z); o.w = f2bf(v.w);
    *(ushort4*)(&xs[r][q]) = o;
  }
  __syncthreads();
  const int g  = lane >> 4;
  const int cl = lane & 15;
  const int nb = n0 + w*16;
  f32x4 acc[4];
  #pragma unroll
  for (int c = 0; c < 4; c++) acc[c] = (f32x4){0.f,0.f,0.f,0.f};
  #pragma unroll
  for (int t = 0; t < 4; t++){
    bf16x8 a = *(const bf16x8*)(&xs[w*16 + cl][t*32 + g*8]);
    #pragma unroll
    for (int c = 0; c < 4; c++){
      bf16x8 bv = *(const bf16x8*)(WTa + (size_t)(c*16 + cl)*IN_DIM + t*32 + g*8);
      acc[c] = __builtin_amdgcn_mfma_f32_16x16x32_bf16(a, bv, acc[c], 0, 0, 0);
    }
  }
  float pes[4][4], ped[4][4];
  #pragma unroll
  for (int h = 0; h < 4; h++)
    #pragma unroll
    for (int j = 0; j < 4; j++){ pes[h][j] = 0.f; ped[h][j] = 0.f; }
  #pragma unroll
  for (int c = 0; c < 4; c++){
    int col = c*16 + cl;
    float bb = b_[col];
    #pragma unroll
    for (int j = 0; j < 4; j++) acc[c][j] += bb;
    #pragma unroll
    for (int h = 0; h < 4; h++){
      float sv = ws0[h*64 + col];
      float dv = wd0[h*64 + col];
      #pragma unroll
      for (int j = 0; j < 4; j++){
        pes[h][j] = fmaf(acc[c][j], sv, pes[h][j]);
        ped[h][j] = fmaf(acc[c][j], dv, ped[h][j]);
      }
    }
  }
  #pragma unroll
  for (int off = 8; off >= 1; off >>= 1){
    #pragma unroll
    for (int h = 0; h < 4; h++)
      #pragma unroll
      for (int j = 0; j < 4; j++){
        pes[h][j] += __shfl_xor(pes[h][j], off);
        ped[h][j] += __shfl_xor(ped[h][j], off);
      }
  }
  if (cl == 0){
    #pragma unroll
    for (int j = 0; j < 4; j++){
      int n = nb + g*4 + j;
      if (n < N_NODES){
        float4 pv; pv.x=pes[0][j]; pv.y=pes[1][j]; pv.z=pes[2][j]; pv.w=pes[3][j];
        float4 qv; qv.x=ped[0][j]; qv.y=ped[1][j]; qv.z=ped[2][j]; qv.w=ped[3][j];
        *(float4*)(es + n*4) = pv;
        *(float4*)(ed + n*4) = qv;
      }
    }
  }
  #pragma unroll
  for (int c = 0; c < 4; c++){
    #pragma unroll
    for (int j = 0; j < 4; j++){
      int n = nb + g*4 + j;
      if (n < N_NODES) x0[(size_t)n*HID + c*16 + cl] = f2bf(acc[c][j]);
    }
  }
}

// ---------------- layer-0 aggregation: gather x0 (128B rows), 4-head weighted sums ----------------
__global__ __launch_bounds__(256) void gat_agg0(const unsigned short* __restrict__ x0,
    const float* __restrict__ es, const float* __restrict__ ed,
    const int* __restrict__ row_start, const int* __restrict__ csr_src,
    unsigned short* __restrict__ y4){
  __shared__ int   sbuf[4][64];
  __shared__ float wbuf[4][64][4];
  const int lane = threadIdx.x & 63;
  const int wid  = threadIdx.x >> 6;
  const int n = blockIdx.x*4 + wid;
  if (n >= N_NODES) return;
  const int rs = row_start[n], re = row_start[n+1];
  const float4 edn = *(const float4*)(ed + n*4);
  const int slot = lane >> 3;
  const int f8   = lane & 7;
  float4 sumw = make_float4(0.f,0.f,0.f,0.f);
  float acc[4][8];
  #pragma unroll
  for (int h=0;h<4;h++)
    #pragma unroll
    for (int q2=0;q2<8;q2++) acc[h][q2]=0.f;

  for (int base = rs; base < re; base += 64){
    const int cl = min(64, re - base);
    int e = base + lane;
    int s = (e < re) ? csr_src[e] : 0;
    float4 e4 = *(const float4*)(es + (s<<2));
    float w0 = __expf(lrelu(e4.x + edn.x));
    float w1 = __expf(lrelu(e4.y + edn.y));
    float w2 = __expf(lrelu(e4.z + edn.z));
    float w3 = __expf(lrelu(e4.w + edn.w));
    if (e >= re){ w0=0.f; w1=0.f; w2=0.f; w3=0.f; }
    sumw.x += w0; sumw.y += w1; sumw.z += w2; sumw.w += w3;
    sbuf[wid][lane] = s;
    float4 wv; wv.x=w0; wv.y=w1; wv.z=w2; wv.w=w3;
    *(float4*)wbuf[wid][lane] = wv;
    int j = 0;
    for (; j + 16 <= cl; j += 16){
      int j0 = j + slot, j1 = j + 8 + slot;
      float4 awA = *(const float4*)wbuf[wid][j0]; int sA = sbuf[wid][j0];
      float4 awB = *(const float4*)wbuf[wid][j1]; int sB = sbuf[wid][j1];
      uint4 hvA = *(const uint4*)(x0 + ((unsigned)(sA<<6) + (unsigned)(f8<<3)));
      uint4 hvB = *(const uint4*)(x0 + ((unsigned)(sB<<6) + (unsigned)(f8<<3)));
      float fA[8] = {bflo(hvA.x),bfhi(hvA.x),bflo(hvA.y),bfhi(hvA.y),
                     bflo(hvA.z),bfhi(hvA.z),bflo(hvA.w),bfhi(hvA.w)};
      float fB[8] = {bflo(hvB.x),bfhi(hvB.x),bflo(hvB.y),bfhi(hvB.y),
                     bflo(hvB.z),bfhi(hvB.z),bflo(hvB.w),bfhi(hvB.w)};
      #pragma unroll
      for (int q2=0;q2<8;q2++){
        acc[0][q2] = fmaf(awA.x, fA[q2], acc[0][q2]);
        acc[1][q2] = fmaf(awA.y, fA[q2], acc[1][q2]);
        acc[2][q2] = fmaf(awA.z, fA[q2], acc[2][q2]);
        acc[3][q2] = fmaf(awA.w, fA[q2], acc[3][q2]);
      }
      #pragma unroll
      for (int q2=0;q2<8;q2++){
        acc[0][q2] = fmaf(awB.x, fB[q2], acc[0][q2]);
        acc[1][q2] = fmaf(awB.y, fB[q2], acc[1][q2]);
        acc[2][q2] = fmaf(awB.z, fB[q2], acc[2][q2]);
        acc[3][q2] = fmaf(awB.w, fB[q2], acc[3][q2]);
      }
    }
    for (; j < cl; j += 8){
      int jj = j + slot;
      if (jj < cl){
        float4 aw = *(const float4*)wbuf[wid][jj];
        int s2 = sbuf[wid][jj];
        uint4 hv = *(const uint4*)(x0 + ((unsigned)(s2<<6) + (unsigned)(f8<<3)));
        float f[8] = {bflo(hv.x),bfhi(hv.x),bflo(hv.y),bfhi(hv.y),
                      bflo(hv.z),bfhi(hv.z),bflo(hv.w),bfhi(hv.w)};
        #pragma unroll
        for (int q2=0;q2<8;q2++){
          acc[0][q2] = fmaf(aw.x, f[q2], acc[0][q2]);
          acc[1][q2] = fmaf(aw.y, f[q2], acc[1][q2]);
          acc[2][q2] = fmaf(aw.z, f[q2], acc[2][q2]);
          acc[3][q2] = fmaf(aw.w, f[q2], acc[3][q2]);
        }
      }
    }
  }
  #pragma unroll
  for (int off = 8; off <= 32; off <<= 1){
    #pragma unroll
    for (int h=0;h<4;h++)
      #pragma unroll
      for (int q2=0;q2<8;q2++) acc[h][q2] += __shfl_xor(acc[h][q2], off);
  }
  #pragma unroll
  for (int off = 32; off >= 1; off >>= 1){
    sumw.x += __shfl_xor(sumw.x, off);
    sumw.y += __shfl_xor(sumw.y, off);
    sumw.z += __shfl_xor(sumw.z, off);
    sumw.w += __shfl_xor(sumw.w, off);
  }
  if (lane < 32){
    int h = lane >> 3;
    float inv = 1.f / (sel4(sumw, h) + 1e-16f);
    union { unsigned short u[8]; uint4 v; } ob;
    #pragma unroll
    for (int q2=0;q2<8;q2++) ob.u[q2] = f2bf(acc[h][q2] * inv);
    *(uint4*)(y4 + (size_t)n*HC + lane*8) = ob.v;
  }
}

// ---------------- fused: x1 = ELU(y4@W0_bd + b0) in LDS, then h1 = x1@W1 + scores ----------------
__global__ __launch_bounds__(256) void hfuse_k(const unsigned short* __restrict__ y4,
                                               const unsigned short* __restrict__ WT0,
                                               const float* __restrict__ b0,
                                               const unsigned short* __restrict__ WT1,
                                               const float* __restrict__ as_, const float* __restrict__ ad_,
                                               unsigned short* __restrict__ h,
                                               float* __restrict__ es, float* __restrict__ ed){
  __shared__ __align__(16) unsigned short xs[16][264];
  __shared__ __align__(16) unsigned short x1s[16][264];
  const int tid = threadIdx.x;
  const int lane = tid & 63;
  const int w = tid >> 6;
  const int n0 = blockIdx.x * 16;
  for (int i = tid; i < 16*32; i += 256){
    int r = i >> 5, cc = (i & 31) * 8;
    *(uint4*)(&xs[r][cc]) = *(const uint4*)(y4 + (size_t)(n0+r)*HC + cc);
  }
  __syncthreads();
  const int g = lane >> 4, cl = lane & 15;
  {
    f32x4 acc[4];
    #pragma unroll
    for (int c = 0; c < 4; c++) acc[c] = (f32x4){0.f,0.f,0.f,0.f};
    #pragma unroll
    for (int t = 0; t < 2; t++){
      bf16x8 a = *(const bf16x8*)(&xs[cl][w*64 + t*32 + g*8]);
      #pragma unroll
      for (int c = 0; c < 4; c++){
        bf16x8 bv = *(const bf16x8*)(WT0 + (size_t)(w*64 + c*16 + cl)*64 + t*32 + g*8);
        acc[c] = __builtin_amdgcn_mfma_f32_16x16x32_bf16(a, bv, acc[c], 0, 0, 0);
      }
    }
    #pragma unroll
    for (int c = 0; c < 4; c++){
      int col = w*64 + c*16 + cl;
      float bb = b0[col];
      #pragma unroll
      for (int j = 0; j < 4; j++){
        float v = acc[c][j] + bb;
        v = v > 0.f ? v : expm1f(v);
        x1s[g*4 + j][col] = f2bf(v);
      }
    }
  }
  __syncthreads();
  f32x4 acc[4];
  #pragma unroll
  for (int c = 0; c < 4; c++) acc[c] = (f32x4){0.f,0.f,0.f,0.f};
  #pragma unroll
  for (int t = 0; t < 8; t++){
    bf16x8 a = *(const bf16x8*)(&x1s[cl][t*32 + g*8]);
    #pragma unroll
    for (int c = 0; c < 4; c++){
      bf16x8 bv = *(const bf16x8*)(WT1 + (size_t)(w*64 + c*16 + cl)*HC + t*32 + g*8);
      acc[c] = __builtin_amdgcn_mfma_f32_16x16x32_bf16(a, bv, acc[c], 0, 0, 0);
    }
  }
  float pes[4] = {0.f,0.f,0.f,0.f}, ped[4] = {0.f,0.f,0.f,0.f};
  #pragma unroll
  for (int c = 0; c < 4; c++){
    float av = as_[w*64 + c*16 + cl];
    float dv = ad_[w*64 + c*16 + cl];
    #pragma unroll
    for (int j = 0; j < 4; j++){
      pes[j] = fmaf(acc[c][j], av, pes[j]);
      ped[j] = fmaf(acc[c][j], dv, ped[j]);
    }
  }
  #pragma unroll
  for (int off = 8; off >= 1; off >>= 1){
    #pragma unroll
    for (int j = 0; j < 4; j++){
      pes[j] += __shfl_xor(pes[j], off);
      ped[j] += __shfl_xor(ped[j], off);
    }
  }
  if (cl == 0){
    #pragma unroll
    for (int j = 0; j < 4; j++){
      int n = n0 + g*4 + j;
      es[n*4 + w] = pes[j];
      ed[n*4 + w] = ped[j];
    }
  }
  #pragma unroll
  for (int c = 0; c < 4; c++){
    #pragma unroll
    for (int j = 0; j < 4; j++){
      h[(size_t)(n0 + g*4 + j)*HC + w*64 + c*16 + cl] = f2bf(acc[c][j]);
    }
  }
}

// ---------------- MFMA GAT linear + fused scores; h NODE-major [N,256] ----------------
template<int K>
__global__ __launch_bounds__(256) void lin_mfma(const unsigned short* __restrict__ x,
                                                const unsigned short* __restrict__ WT,
                                                const float* __restrict__ as_, const float* __restrict__ ad_,
                                                unsigned short* __restrict__ h,
                                                float* __restrict__ es, float* __restrict__ ed){
  constexpr int KP = K + 8;
  __shared__ __align__(16) unsigned short xs[16][KP];
  const int tid = threadIdx.x;
  const int lane = tid & 63;
  const int w = tid >> 6;
  const int n0 = blockIdx.x * 16;
  constexpr int CH = K/8;
  for (int i = tid; i < 16*CH; i += 256){
    int r = i / CH, cc = (i % CH)*8;
    *(uint4*)(&xs[r][cc]) = *(const uint4*)(x + (size_t)(n0+r)*K + cc);
  }
  __syncthreads();
  const int g  = lane >> 4;
  const int cl = lane & 15;
  f32x4 acc[4];
  #pragma unroll
  for (int c = 0; c < 4; c++) acc[c] = (f32x4){0.f,0.f,0.f,0.f};
  #pragma unroll
  for (int t = 0; t < K/32; t++){
    bf16x8 a = *(const bf16x8*)(&xs[cl][t*32 + g*8]);
    #pragma unroll
    for (int c = 0; c < 4; c++){
      bf16x8 bv = *(const bf16x8*)(WT + (size_t)(w*64 + c*16 + cl)*K + t*32 + g*8);
      acc[c] = __builtin_amdgcn_mfma_f32_16x16x32_bf16(a, bv, acc[c], 0, 0, 0);
    }
  }
  float pes[4] = {0.f,0.f,0.f,0.f}, ped[4] = {0.f,0.f,0.f,0.f};
  #pragma unroll
  for (int c = 0; c < 4; c++){
    float av = as_[w*64 + c*16 + cl];
    float dv = ad_[w*64 + c*16 + cl];
    #pragma unroll
    for (int j = 0; j < 4; j++){
      pes[j] = fmaf(acc[c][j], av, pes[j]);
      ped[j] = fmaf(acc[c][j], dv, ped[j]);
    }
  }
  #pragma unroll
  for (int off = 8; off >= 1; off >>= 1){
    #pragma unroll
    for (int j = 0; j < 4; j++){
      pes[j] += __shfl_xor(pes[j], off);
      ped[j] += __shfl_xor(ped[j], off);
    }
  }
  if (cl == 0){
    #pragma unroll
    for (int j = 0; j < 4; j++){
      int n = n0 + g*4 + j;
      es[n*4 + w] = pes[j];
      ed[n*4 + w] = ped[j];
    }
  }
  #pragma unroll
  for (int c = 0; c < 4; c++){
    #pragma unroll
    for (int j = 0; j < 4; j++){
      h[(size_t)(n0 + g*4 + j)*HC + w*64 + c*16 + cl] = f2bf(acc[c][j]);
    }
  }
}

// ---------------- GAT aggregation: 4 heads, 512B rows, 8 edges/iter ----------------
template<int ACT, int OUT64>
__global__ __launch_bounds__(256) void gat_agg(const unsigned short* __restrict__ h,
    const float* __restrict__ es, const float* __restrict__ ed,
    const int* __restrict__ row_start, const int* __restrict__ csr_src,
    const float* __restrict__ bias, unsigned short* __restrict__ outp){
  __shared__ int   sbuf[4][64];
  __shared__ float wbuf[4][64][4];
  const int lane = threadIdx.x & 63;
  const int wid  = threadIdx.x >> 6;
  const int n = blockIdx.x*4 + wid;
  if (n >= N_NODES) return;
  const int rs = row_start[n], re = row_start[n+1];
  const float4 edn = *(const float4*)(ed + n*4);
  const int half = lane >> 5;
  const int l5   = lane & 31;
  const int hh   = l5 >> 3;
  const unsigned voff_lane = (unsigned)(l5 << 3);

  float4 sum4 = make_float4(0.f,0.f,0.f,0.f);
  float a0=0.f,a1=0.f,a2=0.f,a3=0.f,a4=0.f,a5=0.f,a6=0.f,a7=0.f;

  for (int base = rs; base < re; base += 64){
    const int cl = min(64, re - base);
    int e = base + lane;
    int s = (e < re) ? csr_src[e] : 0;
    float4 e4 = *(const float4*)(es + (s<<2));
    float w0 = __expf(lrelu(e4.x + edn.x));
    float w1 = __expf(lrelu(e4.y + edn.y));
    float w2 = __expf(lrelu(e4.z + edn.z));
    float w3 = __expf(lrelu(e4.w + edn.w));
    if (e >= re){ w0=0.f; w1=0.f; w2=0.f; w3=0.f; }
    sum4.x += w0; sum4.y += w1; sum4.z += w2; sum4.w += w3;
    sbuf[wid][lane] = s;
    float4 wv4; wv4.x=w0; wv4.y=w1; wv4.z=w2; wv4.w=w3;
    *(float4*)wbuf[wid][lane] = wv4;
    int j = 0;
    for (; j + 8 <= cl; j += 8){
      int j0 = j + half, j1 = j + 2 + half, j2 = j + 4 + half, j3 = j + 6 + half;
      float aA = wbuf[wid][j0][hh]; int sA = sbuf[wid][j0];
      float aB = wbuf[wid][j1][hh]; int sB = sbuf[wid][j1];
      float aC = wbuf[wid][j2][hh]; int sC = sbuf[wid][j2];
      float aD = wbuf[wid][j3][hh]; int sD = sbuf[wid][j3];
      uint4 hA = *(const uint4*)(h + ((unsigned)(sA<<8) + voff_lane));
      uint4 hB = *(const uint4*)(h + ((unsigned)(sB<<8) + voff_lane));
      uint4 hC = *(const uint4*)(h + ((unsigned)(sC<<8) + voff_lane));
      uint4 hD = *(const uint4*)(h + ((unsigned)(sD<<8) + voff_lane));
      a0 = fmaf(aA, bflo(hA.x), a0); a1 = fmaf(aA, bfhi(hA.x), a1);
      a2 = fmaf(aA, bflo(hA.y), a2); a3 = fmaf(aA, bfhi(hA.y), a3);
      a4 = fmaf(aA, bflo(hA.z), a4); a5 = fmaf(aA, bfhi(hA.z), a5);
      a6 = fmaf(aA, bflo(hA.w), a6); a7 = fmaf(aA, bfhi(hA.w), a7);
      a0 = fmaf(aB, bflo(hB.x), a0); a1 = fmaf(aB, bfhi(hB.x), a1);
      a2 = fmaf(aB, bflo(hB.y), a2); a3 = fmaf(aB, bfhi(hB.y), a3);
      a4 = fmaf(aB, bflo(hB.z), a4); a5 = fmaf(aB, bfhi(hB.z), a5);
      a6 = fmaf(aB, bflo(hB.w), a6); a7 = fmaf(aB, bfhi(hB.w), a7);
      a0 = fmaf(aC, bflo(hC.x), a0); a1 = fmaf(aC, bfhi(hC.x), a1);
      a2 = fmaf(aC, bflo(hC.y), a2); a3 = fmaf(aC, bfhi(hC.y), a3);
      a4 = fmaf(aC, bflo(hC.z), a4); a5 = fmaf(aC, bfhi(hC.z), a5);
      a6 = fmaf(aC, bflo(hC.w), a6); a7 = fmaf(aC, bfhi(hC.w), a7);
      a0 = fmaf(aD, bflo(hD.x), a0); a1 = fmaf(aD, bfhi(hD.x), a1);
      a2 = fmaf(aD, bflo(hD.y), a2); a3 = fmaf(aD, bfhi(hD.y), a3);
      a4 = fmaf(aD, bflo(hD.z), a4); a5 = fmaf(aD, bfhi(hD.z), a5);
      a6 = fmaf(aD, bflo(hD.w), a6); a7 = fmaf(aD, bfhi(hD.w), a7);
    }
    for (; j < cl; j += 2){
      int jj = j + half;
      float a  = wbuf[wid][jj][hh];
      int   s2 = sbuf[wid][jj];
      uint4 hv = *(const uint4*)(h + ((unsigned)(s2<<8) + voff_lane));
      a0 = fmaf(a, bflo(hv.x), a0); a1 = fmaf(a, bfhi(hv.x), a1);
      a2 = fmaf(a, bflo(hv.y), a2); a3 = fmaf(a, bfhi(hv.y), a3);
      a4 = fmaf(a, bflo(hv.z), a4); a5 = fmaf(a, bfhi(hv.z), a5);
      a6 = fmaf(a, bflo(hv.w), a6); a7 = fmaf(a, bfhi(hv.w), a7);
    }
  }
  #pragma unroll
  for (int off = 32; off >= 1; off >>= 1){
    sum4.x += __shfl_xor(sum4.x, off);
    sum4.y += __shfl_xor(sum4.y, off);
    sum4.z += __shfl_xor(sum4.z, off);
    sum4.w += __shfl_xor(sum4.w, off);
  }
  const float inv = 1.f / (sel4(sum4, hh) + 1e-16f);
  a0 += __shfl_xor(a0, 32); a1 += __shfl_xor(a1, 32);
  a2 += __shfl_xor(a2, 32); a3 += __shfl_xor(a3, 32);
  a4 += __shfl_xor(a4, 32); a5 += __shfl_xor(a5, 32);
  a6 += __shfl_xor(a6, 32); a7 += __shfl_xor(a7, 32);
  float4 o;
  o.x = (half ? a4 : a0) * inv;
  o.y = (half ? a5 : a1) * inv;
  o.z = (half ? a6 : a2) * inv;
  o.w = (half ? a7 : a3) * inv;
  if (ACT){
    const int fbase = l5*8 + half*4;
    float4 b4 = *(const float4*)(bias + fbase);
    o.x += b4.x; o.y += b4.y; o.z += b4.z; o.w += b4.w;
    o.x = o.x > 0.f ? o.x : expm1f(o.x);
    o.y = o.y > 0.f ? o.y : expm1f(o.y);
    o.z = o.z > 0.f ? o.z : expm1f(o.z);
    o.w = o.w > 0.f ? o.w : expm1f(o.w);
  }
  if (OUT64){
    o.x += __shfl_xor(o.x, 8); o.y += __shfl_xor(o.y, 8);
    o.z += __shfl_xor(o.z, 8); o.w += __shfl_xor(o.w, 8);
    o.x += __shfl_xor(o.x, 16); o.y += __shfl_xor(o.y, 16);
    o.z += __shfl_xor(o.z, 16); o.w += __shfl_xor(o.w, 16);
    if (l5 < 8){
      ushort4 ob;
      ob.x = f2bf(0.25f*o.x); ob.y = f2bf(0.25f*o.y);
      ob.z = f2bf(0.25f*o.z); ob.w = f2bf(0.25f*o.w);
      *(ushort4*)(outp + (size_t)n*HID + l5*8 + half*4) = ob;
    }
  } else {
    const int fbase = l5*8 + half*4;
    ushort4 ob;
    ob.x = f2bf(o.x); ob.y = f2bf(o.y); ob.z = f2bf(o.z); ob.w = f2bf(o.w);
    *(ushort4*)(outp + (size_t)n*HC + fbase) = ob;
  }
}

// ---------------- global mean pool (bf16 64-dim input) ----------------
#define PB_NODES 64
__global__ __launch_bounds__(256) void pool_k(const unsigned short* __restrict__ x64,
                                              const int* __restrict__ batch, float* __restrict__ pooled,
                                              float* __restrict__ cnt){
  int c = threadIdx.x & 63;
  int sub = threadIdx.x >> 6;
  int n0 = blockIdx.x * PB_NODES;
  int nend = n0 + PB_NODES; if (nend > N_NODES) nend = N_NODES;
  float acc = 0.f; int curg = -1; int cl = 0;
  for (int n = n0 + sub; n < nend; n += 4){
    int g = batch[n];
    if (g != curg){
      if (curg >= 0){
        unsafeAtomicAdd(pooled + curg*HID + c, acc);
        if (c == 0) unsafeAtomicAdd(cnt + curg, (float)cl);
      }
      curg = g; acc = 0.f; cl = 0;
    }
    acc += bf2f(x64[(size_t)n*HID + c]);
    cl++;
  }
  if (curg >= 0){
    unsafeAtomicAdd(pooled + curg*HID + c, acc);
    if (c == 0) unsafeAtomicAdd(cnt + curg, (float)cl);
  }
}

// ---------------- MLP head ----------------
__global__ __launch_bounds__(64) void mlp_k(const float* __restrict__ pooled, const float* __restrict__ cnt,
                                            const float* __restrict__ b2,
                                            const float* __restrict__ mW1, const float* __restrict__ mb1,
                                            const float* __restrict__ mW2, const float* __restrict__ mb2,
                                            float* __restrict__ out){
  __shared__ float p[HID], h1[HID];
  int g = blockIdx.x, j = threadIdx.x;
  float c = fmaxf(cnt[g], 1.f);
  p[j] = pooled[g*HID + j] / c + b2[j];
  __syncthreads();
  float acc = mb1[j];
  #pragma unroll 8
  for (int k = 0; k < HID; k++) acc = fmaf(p[k], mW1[k*HID + j], acc);
  h1[j] = fmaxf(acc, 0.f);
  __syncthreads();
  if (j < OUT_DIM){
    float a2 = mb2[j];
    #pragma unroll 8
    for (int k = 0; k < HID; k++) a2 = fmaf(h1[k], mW2[k*OUT_DIM + j], a2);
    out[g*OUT_DIM + j] = a2;
  }
}

extern "C" void kernel_launch(void* const* d_in, const int* in_sizes, int n_in,
                              void* d_out, int out_size, void* d_ws, size_t ws_size,
                              hipStream_t stream){
  const float* imgs  = (const float*)d_in[0];
  const int*   ei    = (const int*)d_in[1];
  const int*   batch = (const int*)d_in[2];
  const float* W_agg = (const float*)d_in[3];
  const float* b_agg = (const float*)d_in[4];
  const float* W0 = (const float*)d_in[5];
  const float* as0 = (const float*)d_in[6];
  const float* ad0 = (const float*)d_in[7];
  const float* b0 = (const float*)d_in[8];
  const float* W1 = (const float*)d_in[9];
  const float* as1 = (const float*)d_in[10];
  const float* ad1 = (const float*)d_in[11];
  const float* b1 = (const float*)d_in[12];
  const float* W2 = (const float*)d_in[13];
  const float* as2 = (const float*)d_in[14];
  const float* ad2 = (const float*)d_in[15];
  const float* b2 = (const float*)d_in[16];
  const float* mW1 = (const float*)d_in[17];
  const float* mb1 = (const float*)d_in[18];
  const float* mW2 = (const float*)d_in[19];
  const float* mb2 = (const float*)d_in[20];
  float* out = (float*)d_out;

  // workspace layout
  unsigned short* y4  = (unsigned short*)d_ws;                  // N*256 bf16
  unsigned short* hb  = y4 + (size_t)N_NODES*HC;                // N*256 bf16 node-major h
  unsigned short* xbf = hb + (size_t)N_NODES*HC;                // N*256 bf16 (x2) / N*64 (head-mean out)
  float* es   = (float*)(xbf + (size_t)N_NODES*HC);             // N*4
  float* ed   = es + (size_t)N_NODES*HEADS;                     // N*4
  float* pooled = ed + (size_t)N_NODES*HEADS;                   // 64*64 (+64 cnt, contiguous)
  float* cnt  = pooled + N_GRAPHS*HID;                          // 64
  float* ws0  = cnt + N_GRAPHS;                                 // 256
  float* wd0  = ws0 + 256;                                      // 256
  int* row_start = (int*)(wd0 + 256);                           // N+1
  int* csr_src   = row_start + (N_NODES+1);                     // E_TOT
  int* bucket_cursor = csr_src + E_TOT;                         // NBUK
  int* bucket_base   = bucket_cursor + NBUK;                    // NBUK (unused, kept for layout)
  unsigned short* WTa = (unsigned short*)(bucket_base + NBUK);  // 64*128
  unsigned short* WT0 = WTa + 64*128;                           // 256*64
  unsigned short* WT1 = WT0 + 256*64;                           // 256*256
  unsigned short* WT2 = WT1 + 256*256;                          // 256*256
  unsigned int* bucket_buf = (unsigned int*)(WT2 + 256*256);    // NBUK*CAP
  unsigned short* x0bf = (unsigned short*)bucket_buf;           // overlay: N*64 bf16 (buckets dead)

  // CSR build (scan folded into build_k)
  hipMemsetAsync(bucket_cursor, 0, NBUK*sizeof(int), stream);
  bin_k<<<(E_TOT + BT - 1)/BT, 256, 0, stream>>>(ei, bucket_cursor, bucket_buf);
  build_k<<<NBUK, 256, 0, stream>>>(bucket_buf, bucket_cursor, row_start, csr_src);

  // fused weight prep (WTa/WT0/WT1/WT2 + ws0/wd0 + pooled zeroing)
  prep_k<<<609, 256, 0, stream>>>(W_agg, W0, W1, W2, as0, ad0, WTa, WT0, WT1, WT2, ws0, wd0, pooled);

  const int MB = N_NODES/16;            // 3125
  const int GB = (N_NODES + 3)/4;       // 12500
  const int AB = (N_NODES + 63)/64;     // 782

  // MFMA aggregator linear -> bf16 x0 + layer-0 scores
  agg_mfma<<<AB, 256, 0, stream>>>(imgs, WTa, b_agg, ws0, wd0, x0bf, es, ed);

  // layer 0: aggregate x0 (4-head)
  gat_agg0<<<GB, 256, 0, stream>>>(x0bf, es, ed, row_start, csr_src, y4);

  // fused: hgemm (x1) + layer-1 linear + scores
  hfuse_k<<<MB, 256, 0, stream>>>(y4, WT0, b0, WT1, as1, ad1, hb, es, ed);
  gat_agg<1,0><<<GB, 256, 0, stream>>>(hb, es, ed, row_start, csr_src, b1, xbf);

  // layer 2
  lin_mfma<256><<<MB, 256, 0, stream>>>(xbf, WT2, as2, ad2, hb, es, ed);
  gat_agg<0,1><<<GB, 256, 0, stream>>>(hb, es, ed, row_start, csr_src, nullptr, xbf);

  // pool + MLP (bf16 64-dim pool input; pooled pre-zeroed by prep_k)
  pool_k<<<(N_NODES + PB_NODES - 1)/PB_NODES, 256, 0, stream>>>(xbf, batch, pooled, cnt);
  mlp_k<<<N_GRAPHS, 64, 0, stream>>>(pooled, cnt, b2, mW1, mb1, mW2, mb2, out);
}